// Round 1
// baseline (660.267 us; speedup 1.0000x reference)
//
#include <hip/hip_runtime.h>
#include <cstdint>
#include <cstddef>

#define DEVINL __device__ __forceinline__

typedef __bf16 bf16x8 __attribute__((ext_vector_type(8)));
typedef float  f32x4  __attribute__((ext_vector_type(4)));

// ---------------- helpers ----------------

DEVINL unsigned short f2b(float f) {   // f32 -> bf16 bits, round-to-nearest-even
  unsigned u = __builtin_bit_cast(unsigned, f);
  u += 0x7fffu + ((u >> 16) & 1u);
  return (unsigned short)(u >> 16);
}

DEVINL void async16(void* lds, const void* g) {
  // 16B per lane, LDS dest = wave-uniform base + lane*16
  __builtin_amdgcn_global_load_lds((const __attribute__((address_space(1))) unsigned*)g,
                                   (__attribute__((address_space(3))) unsigned*)lds,
                                   16, 0, 0);
}

// ---------------- weight f32 -> bf16 cast ----------------

__global__ void cvt_kernel(const float* __restrict__ in, unsigned short* __restrict__ out, int n4) {
  int i = blockIdx.x * 256 + threadIdx.x;
  if (i < n4) {
    float4 v = ((const float4*)in)[i];
    ushort4 o;
    o.x = f2b(v.x); o.y = f2b(v.y); o.z = f2b(v.z); o.w = f2b(v.w);
    ((ushort4*)out)[i] = o;
  }
}

// ---------------- conditioning: silu(c) @ {shift,scale}_w^T + b ----------------
// grid 32 = 2 batches x 16 col-chunks of 64; block 256 (4 K-slices x 64 cols)

__global__ void cond_kernel(const float* __restrict__ c,
                            const float* __restrict__ scale_w, const float* __restrict__ scale_b,
                            const float* __restrict__ shift_w, const float* __restrict__ shift_b,
                            float* __restrict__ scale_o, float* __restrict__ shift_o) {
  __shared__ float sc[1024];
  __shared__ float red[2][4][64];
  int tid = threadIdx.x;
  int b = blockIdx.x >> 4, ch = blockIdx.x & 15;
  for (int i = tid; i < 1024; i += 256) {
    float cv = c[b * 1024 + i];
    sc[i] = cv / (1.f + __expf(-cv));
  }
  __syncthreads();
  int colidx = tid & 63, p = tid >> 6;
  int co = ch * 64 + colidx;
  float dsc = 0.f, dsh = 0.f;
  for (int i = 0; i < 256; ++i) {
    int kk = p * 256 + i;
    float s = sc[kk];
    dsc += s * scale_w[(size_t)co * 1024 + kk];
    dsh += s * shift_w[(size_t)co * 1024 + kk];
  }
  red[0][p][colidx] = dsc;
  red[1][p][colidx] = dsh;
  __syncthreads();
  if (p == 0) {
    float s4  = red[0][0][colidx] + red[0][1][colidx] + red[0][2][colidx] + red[0][3][colidx];
    float sh4 = red[1][0][colidx] + red[1][1][colidx] + red[1][2][colidx] + red[1][3][colidx];
    scale_o[b * 1024 + co] = fminf(fmaxf(s4 + scale_b[co] + 1.f, 0.1f), 10.f);
    shift_o[b * 1024 + co] = sh4 + shift_b[co];
  }
}

// ---------------- adaLN: h = (x / max(rms,eps)) * norm_w * scale + shift -> bf16 ----------------
// one block (256 thr) per row of 1024

__global__ __launch_bounds__(256) void adaln_kernel(const float* __restrict__ x,
                                                    const float* __restrict__ norm_w,
                                                    const float* __restrict__ scale,
                                                    const float* __restrict__ shift,
                                                    unsigned short* __restrict__ h) {
  int row = blockIdx.x;
  int b = row >> 11;
  int tid = threadIdx.x;
  float4 v = ((const float4*)(x + (size_t)row * 1024))[tid];
  float ss = v.x * v.x + v.y * v.y + v.z * v.z + v.w * v.w;
  #pragma unroll
  for (int d = 32; d; d >>= 1) ss += __shfl_xor(ss, d);
  __shared__ float wsum[4];
  if ((tid & 63) == 0) wsum[tid >> 6] = ss;
  __syncthreads();
  float tot = wsum[0] + wsum[1] + wsum[2] + wsum[3];
  float inv = 1.f / fmaxf(sqrtf(tot * (1.f / 1024.f)), 1e-6f);
  float4 nw  = ((const float4*)norm_w)[tid];
  float4 scv = ((const float4*)(scale + b * 1024))[tid];
  float4 shv = ((const float4*)(shift + b * 1024))[tid];
  ushort4 o;
  o.x = f2b(v.x * inv * nw.x * scv.x + shv.x);
  o.y = f2b(v.y * inv * nw.y * scv.y + shv.y);
  o.z = f2b(v.z * inv * nw.z * scv.z + shv.z);
  o.w = f2b(v.w * inv * nw.w * scv.w + shv.w);
  ((ushort4*)(h + (size_t)row * 1024))[tid] = o;
}

// ---------------- generic 128x128 bf16 MFMA GEMM:  C = A[M,K] @ B[N,K]^T ----------------
// EPI 0: out0(f32) = acc + bias0[col] + resid[row,col]
// EPI 1: QKV scatter -> q (x0.125), k  [B,H,N,D] bf16 ; v [B,H,D,N] bf16
// EPI 2: dual-B GLU: g = silu(acc+b0) * (acc2+b1) -> bf16

template<int EPI>
__global__ __launch_bounds__(256, 1) void gemm_k(
    const unsigned short* __restrict__ A,
    const unsigned short* __restrict__ B0,
    const unsigned short* __restrict__ B1,
    const float* __restrict__ bias0,
    const float* __restrict__ bias1,
    const float* __restrict__ resid,
    void* __restrict__ out0_, void* __restrict__ out1_, void* __restrict__ out2_,
    int M, int N, int K) {
  constexpr bool DUAL = (EPI == 2);
  __shared__ __align__(16) unsigned short As[128 * 32];
  __shared__ __align__(16) unsigned short Bs[128 * 32];
  __shared__ __align__(16) unsigned short Bs2[DUAL ? 128 * 32 : 16];

  const int tid = threadIdx.x;
  const int wave = tid >> 6, lane = tid & 63;
  const int quad = lane >> 4, l16 = lane & 15;
  const int wm = (wave >> 1) * 64, wn = (wave & 1) * 64;
  const int bm = blockIdx.y * 128, bn = blockIdx.x * 128;

  f32x4 acc[4][4] = {};
  f32x4 acc2[DUAL ? 4 : 1][DUAL ? 4 : 1] = {};

  const int steps = K >> 5;
  for (int s = 0; s < steps; ++s) {
    const int k0 = s << 5;
    __syncthreads();
    #pragma unroll
    for (int i = 0; i < 2; ++i) {
      int c = i * 256 + tid;
      int r = c >> 2, ko = (c & 3) << 3;
      unsigned short* lb = (unsigned short*)0;  // silence unused warn pattern
      (void)lb;
      async16(As + (i * 2048 + wave * 512), A + ((size_t)(bm + r) * K + k0 + ko));
      async16(Bs + (i * 2048 + wave * 512), B0 + ((size_t)(bn + r) * K + k0 + ko));
      if constexpr (DUAL)
        async16(Bs2 + (i * 2048 + wave * 512), B1 + ((size_t)(bn + r) * K + k0 + ko));
    }
    __syncthreads();
    bf16x8 af[4], bfr[4];
    #pragma unroll
    for (int mi = 0; mi < 4; ++mi)
      af[mi] = *reinterpret_cast<const bf16x8*>(&As[(wm + mi * 16 + l16) * 32 + quad * 8]);
    #pragma unroll
    for (int ni = 0; ni < 4; ++ni)
      bfr[ni] = *reinterpret_cast<const bf16x8*>(&Bs[(wn + ni * 16 + l16) * 32 + quad * 8]);
    #pragma unroll
    for (int mi = 0; mi < 4; ++mi)
      #pragma unroll
      for (int ni = 0; ni < 4; ++ni)
        acc[mi][ni] = __builtin_amdgcn_mfma_f32_16x16x32_bf16(af[mi], bfr[ni], acc[mi][ni], 0, 0, 0);
    if constexpr (DUAL) {
      bf16x8 bg[4];
      #pragma unroll
      for (int ni = 0; ni < 4; ++ni)
        bg[ni] = *reinterpret_cast<const bf16x8*>(&Bs2[(wn + ni * 16 + l16) * 32 + quad * 8]);
      #pragma unroll
      for (int mi = 0; mi < 4; ++mi)
        #pragma unroll
        for (int ni = 0; ni < 4; ++ni)
          acc2[mi][ni] = __builtin_amdgcn_mfma_f32_16x16x32_bf16(af[mi], bg[ni], acc2[mi][ni], 0, 0, 0);
    }
  }

  // epilogue: C/D layout col=lane&15, row=quad*4+reg
  #pragma unroll
  for (int mi = 0; mi < 4; ++mi) {
    #pragma unroll
    for (int ni = 0; ni < 4; ++ni) {
      int gc = bn + wn + ni * 16 + l16;
      #pragma unroll
      for (int r = 0; r < 4; ++r) {
        int gr = bm + wm + mi * 16 + quad * 4 + r;
        float v = acc[mi][ni][r];
        if constexpr (EPI == 0) {
          ((float*)out0_)[(size_t)gr * N + gc] = v + bias0[gc] + resid[(size_t)gr * N + gc];
        } else if constexpr (EPI == 1) {
          int which = gc >> 10, c2 = gc & 1023, hh = c2 >> 6, d = c2 & 63;
          int b = gr >> 11, n = gr & 2047;
          if (which == 0)
            ((unsigned short*)out0_)[(((size_t)(b * 16 + hh)) * 2048 + n) * 64 + d] = f2b(v * 0.125f);
          else if (which == 1)
            ((unsigned short*)out1_)[(((size_t)(b * 16 + hh)) * 2048 + n) * 64 + d] = f2b(v);
          else
            ((unsigned short*)out2_)[(((size_t)(b * 16 + hh)) * 64 + d) * 2048 + n] = f2b(v);
        } else {
          float a  = v + bias0[gc];
          float b2 = acc2[mi][ni][r] + bias1[gc];
          float g  = (a / (1.f + __expf(-a))) * b2;
          ((unsigned short*)out0_)[(size_t)gr * N + gc] = f2b(g);
        }
      }
    }
  }
}

// ---------------- flash attention ----------------
// q,k: [B,H,N,D] bf16 (q pre-scaled by 0.125);  vt: [B,H,D,N] bf16
// grid (32 bh, 32 qtiles); block 256 = 4 waves x 16 q-rows; out: [B,N,C] bf16

__global__ __launch_bounds__(256, 1) void attn_kernel(
    const unsigned short* __restrict__ q, const unsigned short* __restrict__ k,
    const unsigned short* __restrict__ vt, const int* __restrict__ amask,
    unsigned short* __restrict__ o) {
  const int bh = blockIdx.x;
  const int b = bh >> 4, h = bh & 15;
  const int qt = blockIdx.y;
  const int tid = threadIdx.x;
  const int wave = tid >> 6, lane = tid & 63;
  const int quad = lane >> 4, l16 = lane & 15;

  const unsigned short* qb = q  + (size_t)bh * 2048 * 64;
  const unsigned short* kb = k  + (size_t)bh * 2048 * 64;
  const unsigned short* vb = vt + (size_t)bh * 64 * 2048;

  __shared__ __align__(16) unsigned short Ks[64 * 64];   // [key][d]
  __shared__ __align__(16) unsigned short Vs[64 * 64];   // [d][key]
  __shared__ __align__(16) unsigned short Ps[4][16 * 64];
  __shared__ int msk[64];

  const int qrow = qt * 64 + wave * 16 + l16;
  bf16x8 qa0 = *reinterpret_cast<const bf16x8*>(&qb[(size_t)qrow * 64 + quad * 8]);
  bf16x8 qa1 = *reinterpret_cast<const bf16x8*>(&qb[(size_t)qrow * 64 + 32 + quad * 8]);

  f32x4 oacc[4] = {};
  float mrow[4], lrow[4];
  #pragma unroll
  for (int r = 0; r < 4; ++r) { mrow[r] = -1e30f; lrow[r] = 0.f; }

  for (int kt = 0; kt < 32; ++kt) {
    __syncthreads();
    #pragma unroll
    for (int i = 0; i < 2; ++i) {
      int c = i * 256 + tid;            // 512 chunks of 16B per 8KB tile
      async16(Ks + (i * 2048 + wave * 512), kb + (size_t)kt * 64 * 64 + c * 8);
      int d = c >> 3, koff = (c & 7) * 8;
      async16(Vs + (i * 2048 + wave * 512), vb + (size_t)d * 2048 + kt * 64 + koff);
    }
    if (tid < 64) msk[tid] = amask[b * 2048 + kt * 64 + tid];
    __syncthreads();

    // S = q . k^T  (q pre-scaled)
    f32x4 s[4];
    #pragma unroll
    for (int nt = 0; nt < 4; ++nt) {
      bf16x8 kb0 = *reinterpret_cast<const bf16x8*>(&Ks[(nt * 16 + l16) * 64 + quad * 8]);
      bf16x8 kb1 = *reinterpret_cast<const bf16x8*>(&Ks[(nt * 16 + l16) * 64 + 32 + quad * 8]);
      f32x4 z = {};
      z = __builtin_amdgcn_mfma_f32_16x16x32_bf16(qa0, kb0, z, 0, 0, 0);
      z = __builtin_amdgcn_mfma_f32_16x16x32_bf16(qa1, kb1, z, 0, 0, 0);
      s[nt] = z;
    }
    // mask + row max
    float tmax[4];
    #pragma unroll
    for (int r = 0; r < 4; ++r) tmax[r] = -1e30f;
    #pragma unroll
    for (int nt = 0; nt < 4; ++nt) {
      bool ok = msk[nt * 16 + l16] != 0;
      #pragma unroll
      for (int r = 0; r < 4; ++r) {
        s[nt][r] = ok ? s[nt][r] : -1e30f;
        tmax[r] = fmaxf(tmax[r], s[nt][r]);
      }
    }
    #pragma unroll
    for (int d = 1; d < 16; d <<= 1)
      #pragma unroll
      for (int r = 0; r < 4; ++r) tmax[r] = fmaxf(tmax[r], __shfl_xor(tmax[r], d));

    float mnew[4], alpha[4], rs[4];
    #pragma unroll
    for (int r = 0; r < 4; ++r) {
      mnew[r] = fmaxf(mrow[r], tmax[r]);
      alpha[r] = __expf(mrow[r] - mnew[r]);   // both -1e30 -> exp(0)=1, l stays 0
      mrow[r] = mnew[r];
      rs[r] = 0.f;
    }
    #pragma unroll
    for (int nt = 0; nt < 4; ++nt)
      #pragma unroll
      for (int r = 0; r < 4; ++r) {
        float p = (s[nt][r] > -0.5e30f) ? __expf(s[nt][r] - mnew[r]) : 0.f;
        Ps[wave][(quad * 4 + r) * 64 + nt * 16 + l16] = f2b(p);
        rs[r] += p;
      }
    #pragma unroll
    for (int d = 1; d < 16; d <<= 1)
      #pragma unroll
      for (int r = 0; r < 4; ++r) rs[r] += __shfl_xor(rs[r], d);
    #pragma unroll
    for (int r = 0; r < 4; ++r) lrow[r] = lrow[r] * alpha[r] + rs[r];
    #pragma unroll
    for (int dt = 0; dt < 4; ++dt)
      #pragma unroll
      for (int r = 0; r < 4; ++r) oacc[dt][r] *= alpha[r];

    __syncthreads();  // make P's LDS writes safely visible (paranoia; Ps is per-wave)

    bf16x8 pa0 = *reinterpret_cast<const bf16x8*>(&Ps[wave][l16 * 64 + quad * 8]);
    bf16x8 pa1 = *reinterpret_cast<const bf16x8*>(&Ps[wave][l16 * 64 + 32 + quad * 8]);
    #pragma unroll
    for (int dt = 0; dt < 4; ++dt) {
      bf16x8 vb0 = *reinterpret_cast<const bf16x8*>(&Vs[(dt * 16 + l16) * 64 + quad * 8]);
      bf16x8 vb1 = *reinterpret_cast<const bf16x8*>(&Vs[(dt * 16 + l16) * 64 + 32 + quad * 8]);
      oacc[dt] = __builtin_amdgcn_mfma_f32_16x16x32_bf16(pa0, vb0, oacc[dt], 0, 0, 0);
      oacc[dt] = __builtin_amdgcn_mfma_f32_16x16x32_bf16(pa1, vb1, oacc[dt], 0, 0, 0);
    }
  }

  float invl[4];
  #pragma unroll
  for (int r = 0; r < 4; ++r) invl[r] = lrow[r] > 0.f ? 1.f / lrow[r] : 0.f;
  #pragma unroll
  for (int dt = 0; dt < 4; ++dt)
    #pragma unroll
    for (int r = 0; r < 4; ++r) {
      int row = qt * 64 + wave * 16 + quad * 4 + r;
      int col = h * 64 + dt * 16 + l16;
      o[((size_t)b * 2048 + row) * 1024 + col] = f2b(oacc[dt][r] * invl[r]);
    }
}

// ---------------- launch ----------------

extern "C" void kernel_launch(void* const* d_in, const int* in_sizes, int n_in,
                              void* d_out, int out_size, void* d_ws, size_t ws_size,
                              hipStream_t stream) {
  const float* x       = (const float*)d_in[0];
  const float* c       = (const float*)d_in[1];
  const int*   amask   = (const int*)d_in[2];
  const float* norm_w  = (const float*)d_in[3];
  const float* scale_w = (const float*)d_in[4];
  const float* scale_b = (const float*)d_in[5];
  const float* shift_w = (const float*)d_in[6];
  const float* shift_b = (const float*)d_in[7];
  const float* qkv_w   = (const float*)d_in[8];
  const float* proj_w  = (const float*)d_in[9];
  const float* proj_b  = (const float*)d_in[10];
  const float* mlp_w1  = (const float*)d_in[11];
  const float* mlp_b1  = (const float*)d_in[12];
  const float* mlp_w2  = (const float*)d_in[13];
  const float* mlp_b2  = (const float*)d_in[14];

  char* ws = (char*)d_ws;
  unsigned short* wqkv  = (unsigned short*)(ws + 0);          // 6291456 B
  unsigned short* wproj = (unsigned short*)(ws + 6291456);    // 2097152
  unsigned short* wmlp1 = (unsigned short*)(ws + 8388608);    // 16777216
  unsigned short* wmlp2 = (unsigned short*)(ws + 25165824);   // 8388608
  float* scale_o        = (float*)(ws + 33554432);            // 8192
  float* shift_o        = (float*)(ws + 33562624);            // 8192
  unsigned short* hbuf  = (unsigned short*)(ws + 33570816);   // 8388608
  unsigned short* qbuf  = (unsigned short*)(ws + 41959424);   // 8388608
  unsigned short* kbuf  = (unsigned short*)(ws + 50348032);   // 8388608
  unsigned short* vbuf  = (unsigned short*)(ws + 58736640);   // 8388608
  unsigned short* abuf  = (unsigned short*)(ws + 67125248);   // 8388608
  unsigned short* gbuf  = qbuf;                               // overlays q..attn (33554432)
  float* x1             = (float*)(ws + 75513856);            // 16777216 (end ~92.3MB)

  cvt_kernel<<<3072, 256, 0, stream>>>(qkv_w, wqkv, 786432);
  cvt_kernel<<<1024, 256, 0, stream>>>(proj_w, wproj, 262144);
  cvt_kernel<<<8192, 256, 0, stream>>>(mlp_w1, wmlp1, 2097152);
  cvt_kernel<<<4096, 256, 0, stream>>>(mlp_w2, wmlp2, 1048576);

  cond_kernel<<<32, 256, 0, stream>>>(c, scale_w, scale_b, shift_w, shift_b, scale_o, shift_o);

  adaln_kernel<<<4096, 256, 0, stream>>>(x, norm_w, scale_o, shift_o, hbuf);

  gemm_k<1><<<dim3(24, 32), 256, 0, stream>>>(hbuf, wqkv, nullptr, nullptr, nullptr, nullptr,
                                              qbuf, kbuf, vbuf, 4096, 3072, 1024);

  attn_kernel<<<dim3(32, 32), 256, 0, stream>>>(qbuf, kbuf, vbuf, amask, abuf);

  gemm_k<0><<<dim3(8, 32), 256, 0, stream>>>(abuf, wproj, nullptr, proj_b, nullptr, x,
                                             x1, nullptr, nullptr, 4096, 1024, 1024);

  adaln_kernel<<<4096, 256, 0, stream>>>(x1, norm_w, scale_o, shift_o, hbuf);

  gemm_k<2><<<dim3(32, 32), 256, 0, stream>>>(hbuf, wmlp1, wmlp1 + 4096 * 1024, mlp_b1, mlp_b1 + 4096,
                                              nullptr, gbuf, nullptr, nullptr, 4096, 4096, 1024);

  gemm_k<0><<<dim3(8, 32), 256, 0, stream>>>(gbuf, wmlp2, nullptr, mlp_b2, nullptr, x1,
                                             d_out, nullptr, nullptr, 4096, 1024, 4096);

  (void)in_sizes; (void)n_in; (void)out_size; (void)ws_size;
}

// Round 2
// 648.386 us; speedup vs baseline: 1.0183x; 1.0183x over previous
//
#include <hip/hip_runtime.h>
#include <cstdint>
#include <cstddef>

#define DEVINL __device__ __forceinline__

typedef __bf16 bf16x8 __attribute__((ext_vector_type(8)));
typedef float  f32x4  __attribute__((ext_vector_type(4)));

// ---------------- helpers ----------------

DEVINL unsigned short f2b(float f) {   // f32 -> bf16 bits, round-to-nearest-even
  unsigned u = __builtin_bit_cast(unsigned, f);
  u += 0x7fffu + ((u >> 16) & 1u);
  return (unsigned short)(u >> 16);
}

DEVINL unsigned packtrunc(float a, float b) {  // 2x f32 -> packed bf16 (truncate)
  unsigned ua = __builtin_bit_cast(unsigned, a);
  unsigned ub = __builtin_bit_cast(unsigned, b);
  return (ua >> 16) | (ub & 0xffff0000u);
}

DEVINL void async16(void* lds, const void* g) {
  __builtin_amdgcn_global_load_lds((const __attribute__((address_space(1))) unsigned*)g,
                                   (__attribute__((address_space(3))) unsigned*)lds,
                                   16, 0, 0);
}

// ---------------- weight f32 -> bf16 cast ----------------

__global__ void cvt_kernel(const float* __restrict__ in, unsigned short* __restrict__ out, int n4) {
  int i = blockIdx.x * 256 + threadIdx.x;
  if (i < n4) {
    float4 v = ((const float4*)in)[i];
    ushort4 o;
    o.x = f2b(v.x); o.y = f2b(v.y); o.z = f2b(v.z); o.w = f2b(v.w);
    ((ushort4*)out)[i] = o;
  }
}

// ---------------- conditioning: silu(c) @ {shift,scale}_w^T + b ----------------

__global__ void cond_kernel(const float* __restrict__ c,
                            const float* __restrict__ scale_w, const float* __restrict__ scale_b,
                            const float* __restrict__ shift_w, const float* __restrict__ shift_b,
                            float* __restrict__ scale_o, float* __restrict__ shift_o) {
  __shared__ float sc[1024];
  __shared__ float red[2][4][64];
  int tid = threadIdx.x;
  int b = blockIdx.x >> 4, ch = blockIdx.x & 15;
  for (int i = tid; i < 1024; i += 256) {
    float cv = c[b * 1024 + i];
    sc[i] = cv / (1.f + __expf(-cv));
  }
  __syncthreads();
  int colidx = tid & 63, p = tid >> 6;
  int co = ch * 64 + colidx;
  float dsc = 0.f, dsh = 0.f;
  for (int i = 0; i < 256; ++i) {
    int kk = p * 256 + i;
    float s = sc[kk];
    dsc += s * scale_w[(size_t)co * 1024 + kk];
    dsh += s * shift_w[(size_t)co * 1024 + kk];
  }
  red[0][p][colidx] = dsc;
  red[1][p][colidx] = dsh;
  __syncthreads();
  if (p == 0) {
    float s4  = red[0][0][colidx] + red[0][1][colidx] + red[0][2][colidx] + red[0][3][colidx];
    float sh4 = red[1][0][colidx] + red[1][1][colidx] + red[1][2][colidx] + red[1][3][colidx];
    scale_o[b * 1024 + co] = fminf(fmaxf(s4 + scale_b[co] + 1.f, 0.1f), 10.f);
    shift_o[b * 1024 + co] = sh4 + shift_b[co];
  }
}

// ---------------- adaLN ----------------

__global__ __launch_bounds__(256) void adaln_kernel(const float* __restrict__ x,
                                                    const float* __restrict__ norm_w,
                                                    const float* __restrict__ scale,
                                                    const float* __restrict__ shift,
                                                    unsigned short* __restrict__ h) {
  int row = blockIdx.x;
  int b = row >> 11;
  int tid = threadIdx.x;
  float4 v = ((const float4*)(x + (size_t)row * 1024))[tid];
  float ss = v.x * v.x + v.y * v.y + v.z * v.z + v.w * v.w;
  #pragma unroll
  for (int d = 32; d; d >>= 1) ss += __shfl_xor(ss, d);
  __shared__ float wsum[4];
  if ((tid & 63) == 0) wsum[tid >> 6] = ss;
  __syncthreads();
  float tot = wsum[0] + wsum[1] + wsum[2] + wsum[3];
  float inv = 1.f / fmaxf(sqrtf(tot * (1.f / 1024.f)), 1e-6f);
  float4 nw  = ((const float4*)norm_w)[tid];
  float4 scv = ((const float4*)(scale + b * 1024))[tid];
  float4 shv = ((const float4*)(shift + b * 1024))[tid];
  ushort4 o;
  o.x = f2b(v.x * inv * nw.x * scv.x + shv.x);
  o.y = f2b(v.y * inv * nw.y * scv.y + shv.y);
  o.z = f2b(v.z * inv * nw.z * scv.z + shv.z);
  o.w = f2b(v.w * inv * nw.w * scv.w + shv.w);
  ((ushort4*)(h + (size_t)row * 1024))[tid] = o;
}

// ---------------- 128x128 bf16 MFMA GEMM:  C = A[M,K] @ B[N,K]^T ----------------
// LDS k-chunk XOR swizzle: phys chunk = logical chunk ^ (row & 3). Global fetch
// permutes within each row's 64B (coalescing kept); fragment reads hit all 32 banks.

template<int EPI>
__global__ __launch_bounds__(256, 1) void gemm_k(
    const unsigned short* __restrict__ A,
    const unsigned short* __restrict__ B0,
    const unsigned short* __restrict__ B1,
    const float* __restrict__ bias0,
    const float* __restrict__ bias1,
    const float* __restrict__ resid,
    void* __restrict__ out0_, void* __restrict__ out1_, void* __restrict__ out2_,
    int M, int N, int K) {
  constexpr bool DUAL = (EPI == 2);
  __shared__ __align__(16) unsigned short As[128 * 32];
  __shared__ __align__(16) unsigned short Bs[128 * 32];
  __shared__ __align__(16) unsigned short Bs2[DUAL ? 128 * 32 : 16];

  const int tid = threadIdx.x;
  const int wave = tid >> 6, lane = tid & 63;
  const int quad = lane >> 4, l16 = lane & 15;
  const int wm = (wave >> 1) * 64, wn = (wave & 1) * 64;
  const int bm = blockIdx.y * 128, bn = blockIdx.x * 128;
  const int kx8 = (quad ^ (l16 & 3)) * 8;   // swizzled fragment k-chunk

  f32x4 acc[4][4] = {};
  f32x4 acc2[DUAL ? 4 : 1][DUAL ? 4 : 1] = {};

  const int steps = K >> 5;
  for (int s = 0; s < steps; ++s) {
    const int k0 = s << 5;
    __syncthreads();
    #pragma unroll
    for (int i = 0; i < 2; ++i) {
      int c = i * 256 + tid;
      int r = c >> 2;
      int ko = (((c & 3) ^ (r & 3)) << 3);     // XOR swizzle in global fetch
      async16(As + (i * 2048 + wave * 512), A + ((size_t)(bm + r) * K + k0 + ko));
      async16(Bs + (i * 2048 + wave * 512), B0 + ((size_t)(bn + r) * K + k0 + ko));
      if constexpr (DUAL)
        async16(Bs2 + (i * 2048 + wave * 512), B1 + ((size_t)(bn + r) * K + k0 + ko));
    }
    __syncthreads();
    bf16x8 af[4], bfr[4];
    #pragma unroll
    for (int mi = 0; mi < 4; ++mi)
      af[mi] = *reinterpret_cast<const bf16x8*>(&As[(wm + mi * 16 + l16) * 32 + kx8]);
    #pragma unroll
    for (int ni = 0; ni < 4; ++ni)
      bfr[ni] = *reinterpret_cast<const bf16x8*>(&Bs[(wn + ni * 16 + l16) * 32 + kx8]);
    #pragma unroll
    for (int mi = 0; mi < 4; ++mi)
      #pragma unroll
      for (int ni = 0; ni < 4; ++ni)
        acc[mi][ni] = __builtin_amdgcn_mfma_f32_16x16x32_bf16(af[mi], bfr[ni], acc[mi][ni], 0, 0, 0);
    if constexpr (DUAL) {
      bf16x8 bg[4];
      #pragma unroll
      for (int ni = 0; ni < 4; ++ni)
        bg[ni] = *reinterpret_cast<const bf16x8*>(&Bs2[(wn + ni * 16 + l16) * 32 + kx8]);
      #pragma unroll
      for (int mi = 0; mi < 4; ++mi)
        #pragma unroll
        for (int ni = 0; ni < 4; ++ni)
          acc2[mi][ni] = __builtin_amdgcn_mfma_f32_16x16x32_bf16(af[mi], bg[ni], acc2[mi][ni], 0, 0, 0);
    }
  }

  // epilogue: C/D layout col=lane&15, row=quad*4+reg
  #pragma unroll
  for (int mi = 0; mi < 4; ++mi) {
    #pragma unroll
    for (int ni = 0; ni < 4; ++ni) {
      int gc = bn + wn + ni * 16 + l16;
      #pragma unroll
      for (int r = 0; r < 4; ++r) {
        int gr = bm + wm + mi * 16 + quad * 4 + r;
        float v = acc[mi][ni][r];
        if constexpr (EPI == 0) {
          ((float*)out0_)[(size_t)gr * N + gc] = v + bias0[gc] + resid[(size_t)gr * N + gc];
        } else if constexpr (EPI == 1) {
          int which = gc >> 10, c2 = gc & 1023, hh = c2 >> 6, d = c2 & 63;
          int b = gr >> 11, n = gr & 2047;
          if (which == 0)
            ((unsigned short*)out0_)[(((size_t)(b * 16 + hh)) * 2048 + n) * 64 + d] = f2b(v * 0.125f);
          else if (which == 1)
            ((unsigned short*)out1_)[(((size_t)(b * 16 + hh)) * 2048 + n) * 64 + d] = f2b(v);
          else
            ((unsigned short*)out2_)[(((size_t)(b * 16 + hh)) * 64 + d) * 2048 + n] = f2b(v);
        } else {
          float a  = v + bias0[gc];
          float b2 = acc2[mi][ni][r] + bias1[gc];
          float g  = (a / (1.f + __expf(-a))) * b2;
          ((unsigned short*)out0_)[(size_t)gr * N + gc] = f2b(g);
        }
      }
    }
  }
}

// ---------------- flash attention (S^T formulation) ----------------
// q,k: [B,H,N,D] bf16 (q pre-scaled by 0.125); vt: [B,H,D,N] bf16
// Per wave: 16 q-rows. S^T = K_tile @ Q^T  -> lane(quad,l16) holds
// S[q=l16][key=nt*16+quad*4+r]; row reductions = in-register + 2 shfl_xor.
// K/V staged with XOR-swizzled ds_write_b128 (conflict-free frag reads).
// Mask as additive -30000 bias (reproduces reference all-masked semantics).

__global__ __launch_bounds__(256, 1) void attn_kernel(
    const unsigned short* __restrict__ q, const unsigned short* __restrict__ k,
    const unsigned short* __restrict__ vt, const int* __restrict__ amask,
    unsigned short* __restrict__ o) {
  const int bh = blockIdx.x;
  const int b = bh >> 4, h = bh & 15;
  const int qt = blockIdx.y;
  const int tid = threadIdx.x;
  const int wave = tid >> 6, lane = tid & 63;
  const int quad = lane >> 4, l16 = lane & 15;
  const int h7 = l16 & 7;
  const int kc0 = (quad ^ h7) * 8;          // swizzled chunk, k/v frag half 0
  const int kc1 = ((quad + 4) ^ h7) * 8;    // half 1

  const unsigned short* qb = q  + (size_t)bh * 2048 * 64;
  const unsigned short* kb = k  + (size_t)bh * 2048 * 64;
  const unsigned short* vb = vt + (size_t)bh * 64 * 2048;

  __shared__ __align__(16) unsigned short Ks[64 * 64];     // [key][d], chunk-swizzled
  __shared__ __align__(16) unsigned short Vs[64 * 64];     // [d][key], chunk-swizzled
  __shared__ __align__(16) unsigned short Ps[4][16 * 72];  // padded rows: 144B stride
  __shared__ float biasf[64];

  const int qrow = qt * 64 + wave * 16 + l16;
  bf16x8 qa0 = *reinterpret_cast<const bf16x8*>(&qb[(size_t)qrow * 64 + quad * 8]);
  bf16x8 qa1 = *reinterpret_cast<const bf16x8*>(&qb[(size_t)qrow * 64 + 32 + quad * 8]);
  unsigned short* PsW = &Ps[wave][0];

  f32x4 oacc[4] = {};
  float mrow = -30000.f, lrow = 0.f;

  // prefetch tile 0
  uint4 kpre[2], vpre[2];
  #pragma unroll
  for (int i = 0; i < 2; ++i) {
    int c = i * 256 + tid;
    int key = c >> 3, dl = (c & 7) ^ (key & 7);
    kpre[i] = *(const uint4*)(kb + key * 64 + dl * 8);
    int d = c >> 3, kl = (c & 7) ^ (d & 7);
    vpre[i] = *(const uint4*)(vb + (size_t)d * 2048 + kl * 8);
  }
  int mv = (tid < 64) ? amask[b * 2048 + tid] : 0;

  for (int kt = 0; kt < 32; ++kt) {
    __syncthreads();
    ((uint4*)Ks)[tid]       = kpre[0];
    ((uint4*)Ks)[256 + tid] = kpre[1];
    ((uint4*)Vs)[tid]       = vpre[0];
    ((uint4*)Vs)[256 + tid] = vpre[1];
    if (tid < 64) biasf[tid] = mv ? 0.f : -30000.f;
    __syncthreads();

    if (kt + 1 < 32) {   // prefetch next tile during compute
      #pragma unroll
      for (int i = 0; i < 2; ++i) {
        int c = i * 256 + tid;
        int key = c >> 3, dl = (c & 7) ^ (key & 7);
        kpre[i] = *(const uint4*)(kb + (size_t)(kt + 1) * 4096 + key * 64 + dl * 8);
        int d = c >> 3, kl = (c & 7) ^ (d & 7);
        vpre[i] = *(const uint4*)(vb + (size_t)d * 2048 + (kt + 1) * 64 + kl * 8);
      }
      mv = (tid < 64) ? amask[b * 2048 + (kt + 1) * 64 + tid] : 0;
    }

    // S^T tiles: lane holds S[q=l16][key=nt*16+quad*4+r] + bias
    f32x4 st[4];
    #pragma unroll
    for (int nt = 0; nt < 4; ++nt) {
      bf16x8 ka0 = *reinterpret_cast<const bf16x8*>(&Ks[(nt * 16 + l16) * 64 + kc0]);
      bf16x8 ka1 = *reinterpret_cast<const bf16x8*>(&Ks[(nt * 16 + l16) * 64 + kc1]);
      f32x4 z = {};
      z = __builtin_amdgcn_mfma_f32_16x16x32_bf16(ka0, qa0, z, 0, 0, 0);
      z = __builtin_amdgcn_mfma_f32_16x16x32_bf16(ka1, qa1, z, 0, 0, 0);
      f32x4 bv = *reinterpret_cast<const f32x4*>(&biasf[nt * 16 + quad * 4]);
      st[nt] = z + bv;
    }

    // row max (q=l16): in-register + cross-quad
    float tm = -1e30f;
    #pragma unroll
    for (int nt = 0; nt < 4; ++nt)
      #pragma unroll
      for (int r = 0; r < 4; ++r) tm = fmaxf(tm, st[nt][r]);
    tm = fmaxf(tm, __shfl_xor(tm, 16));
    tm = fmaxf(tm, __shfl_xor(tm, 32));

    float mnew = fmaxf(mrow, tm);
    float alpha = __expf(mrow - mnew);
    mrow = mnew;

    float rs = 0.f;
    #pragma unroll
    for (int nt = 0; nt < 4; ++nt) {
      float p0 = __expf(st[nt][0] - mnew);
      float p1 = __expf(st[nt][1] - mnew);
      float p2 = __expf(st[nt][2] - mnew);
      float p3 = __expf(st[nt][3] - mnew);
      rs += (p0 + p1) + (p2 + p3);
      uint2 w;
      w.x = packtrunc(p0, p1);
      w.y = packtrunc(p2, p3);
      *(uint2*)&PsW[l16 * 72 + nt * 16 + quad * 4] = w;
    }
    rs += __shfl_xor(rs, 16);
    rs += __shfl_xor(rs, 32);
    lrow = lrow * alpha + rs;

    // scale O (rows q'=quad*4+r need alpha from lane l16=q')
    float a0 = __shfl(alpha, quad * 4 + 0);
    float a1 = __shfl(alpha, quad * 4 + 1);
    float a2 = __shfl(alpha, quad * 4 + 2);
    float a3 = __shfl(alpha, quad * 4 + 3);
    #pragma unroll
    for (int dt = 0; dt < 4; ++dt) {
      oacc[dt][0] *= a0; oacc[dt][1] *= a1; oacc[dt][2] *= a2; oacc[dt][3] *= a3;
    }

    // PV: A = P rows (per-wave LDS, no barrier needed), B = V^T rows
    bf16x8 pa0 = *reinterpret_cast<const bf16x8*>(&PsW[l16 * 72 + quad * 8]);
    bf16x8 pa1 = *reinterpret_cast<const bf16x8*>(&PsW[l16 * 72 + 32 + quad * 8]);
    #pragma unroll
    for (int dt = 0; dt < 4; ++dt) {
      bf16x8 vb0 = *reinterpret_cast<const bf16x8*>(&Vs[(dt * 16 + l16) * 64 + kc0]);
      bf16x8 vb1 = *reinterpret_cast<const bf16x8*>(&Vs[(dt * 16 + l16) * 64 + kc1]);
      oacc[dt] = __builtin_amdgcn_mfma_f32_16x16x32_bf16(pa0, vb0, oacc[dt], 0, 0, 0);
      oacc[dt] = __builtin_amdgcn_mfma_f32_16x16x32_bf16(pa1, vb1, oacc[dt], 0, 0, 0);
    }
  }

  float invl = lrow > 0.f ? 1.f / lrow : 0.f;
  float i0 = __shfl(invl, quad * 4 + 0);
  float i1 = __shfl(invl, quad * 4 + 1);
  float i2 = __shfl(invl, quad * 4 + 2);
  float i3 = __shfl(invl, quad * 4 + 3);
  #pragma unroll
  for (int dt = 0; dt < 4; ++dt) {
    int col = h * 64 + dt * 16 + l16;
    int rb = qt * 64 + wave * 16 + quad * 4;
    o[((size_t)b * 2048 + rb + 0) * 1024 + col] = f2b(oacc[dt][0] * i0);
    o[((size_t)b * 2048 + rb + 1) * 1024 + col] = f2b(oacc[dt][1] * i1);
    o[((size_t)b * 2048 + rb + 2) * 1024 + col] = f2b(oacc[dt][2] * i2);
    o[((size_t)b * 2048 + rb + 3) * 1024 + col] = f2b(oacc[dt][3] * i3);
  }
}

// ---------------- launch ----------------

extern "C" void kernel_launch(void* const* d_in, const int* in_sizes, int n_in,
                              void* d_out, int out_size, void* d_ws, size_t ws_size,
                              hipStream_t stream) {
  const float* x       = (const float*)d_in[0];
  const float* c       = (const float*)d_in[1];
  const int*   amask   = (const int*)d_in[2];
  const float* norm_w  = (const float*)d_in[3];
  const float* scale_w = (const float*)d_in[4];
  const float* scale_b = (const float*)d_in[5];
  const float* shift_w = (const float*)d_in[6];
  const float* shift_b = (const float*)d_in[7];
  const float* qkv_w   = (const float*)d_in[8];
  const float* proj_w  = (const float*)d_in[9];
  const float* proj_b  = (const float*)d_in[10];
  const float* mlp_w1  = (const float*)d_in[11];
  const float* mlp_b1  = (const float*)d_in[12];
  const float* mlp_w2  = (const float*)d_in[13];
  const float* mlp_b2  = (const float*)d_in[14];

  char* ws = (char*)d_ws;
  unsigned short* wqkv  = (unsigned short*)(ws + 0);
  unsigned short* wproj = (unsigned short*)(ws + 6291456);
  unsigned short* wmlp1 = (unsigned short*)(ws + 8388608);
  unsigned short* wmlp2 = (unsigned short*)(ws + 25165824);
  float* scale_o        = (float*)(ws + 33554432);
  float* shift_o        = (float*)(ws + 33562624);
  unsigned short* hbuf  = (unsigned short*)(ws + 33570816);
  unsigned short* qbuf  = (unsigned short*)(ws + 41959424);
  unsigned short* kbuf  = (unsigned short*)(ws + 50348032);
  unsigned short* vbuf  = (unsigned short*)(ws + 58736640);
  unsigned short* abuf  = (unsigned short*)(ws + 67125248);
  unsigned short* gbuf  = qbuf;
  float* x1             = (float*)(ws + 75513856);

  cvt_kernel<<<3072, 256, 0, stream>>>(qkv_w, wqkv, 786432);
  cvt_kernel<<<1024, 256, 0, stream>>>(proj_w, wproj, 262144);
  cvt_kernel<<<8192, 256, 0, stream>>>(mlp_w1, wmlp1, 2097152);
  cvt_kernel<<<4096, 256, 0, stream>>>(mlp_w2, wmlp2, 1048576);

  cond_kernel<<<32, 256, 0, stream>>>(c, scale_w, scale_b, shift_w, shift_b, scale_o, shift_o);

  adaln_kernel<<<4096, 256, 0, stream>>>(x, norm_w, scale_o, shift_o, hbuf);

  gemm_k<1><<<dim3(24, 32), 256, 0, stream>>>(hbuf, wqkv, nullptr, nullptr, nullptr, nullptr,
                                              qbuf, kbuf, vbuf, 4096, 3072, 1024);

  attn_kernel<<<dim3(32, 32), 256, 0, stream>>>(qbuf, kbuf, vbuf, amask, abuf);

  gemm_k<0><<<dim3(8, 32), 256, 0, stream>>>(abuf, wproj, nullptr, proj_b, nullptr, x,
                                             x1, nullptr, nullptr, 4096, 1024, 1024);

  adaln_kernel<<<4096, 256, 0, stream>>>(x1, norm_w, scale_o, shift_o, hbuf);

  gemm_k<2><<<dim3(32, 32), 256, 0, stream>>>(hbuf, wmlp1, wmlp1 + 4096 * 1024, mlp_b1, mlp_b1 + 4096,
                                              nullptr, gbuf, nullptr, nullptr, 4096, 4096, 1024);

  gemm_k<0><<<dim3(8, 32), 256, 0, stream>>>(gbuf, wmlp2, nullptr, mlp_b2, nullptr, x1,
                                             d_out, nullptr, nullptr, 4096, 1024, 4096);

  (void)in_sizes; (void)n_in; (void)out_size; (void)ws_size;
}

// Round 3
// 606.453 us; speedup vs baseline: 1.0887x; 1.0691x over previous
//
#include <hip/hip_runtime.h>
#include <cstdint>
#include <cstddef>

#define DEVINL __device__ __forceinline__

typedef __bf16 bf16x8 __attribute__((ext_vector_type(8)));
typedef float  f32x4  __attribute__((ext_vector_type(4)));

// ---------------- helpers ----------------

DEVINL unsigned short f2b(float f) {   // f32 -> bf16 bits, round-to-nearest-even
  unsigned u = __builtin_bit_cast(unsigned, f);
  u += 0x7fffu + ((u >> 16) & 1u);
  return (unsigned short)(u >> 16);
}

DEVINL unsigned packtrunc(float a, float b) {  // 2x f32 -> packed bf16 (truncate)
  unsigned ua = __builtin_bit_cast(unsigned, a);
  unsigned ub = __builtin_bit_cast(unsigned, b);
  return (ua >> 16) | (ub & 0xffff0000u);
}

DEVINL void async16(void* lds, const void* g) {
  __builtin_amdgcn_global_load_lds((const __attribute__((address_space(1))) unsigned*)g,
                                   (__attribute__((address_space(3))) unsigned*)lds,
                                   16, 0, 0);
}

// ---------------- fused weight f32 -> bf16 cast (all 4 weights, 1 launch) ----------------

__global__ void cvt4_kernel(const float* __restrict__ s0, const float* __restrict__ s1,
                            const float* __restrict__ s2, const float* __restrict__ s3,
                            unsigned short* __restrict__ d0, unsigned short* __restrict__ d1,
                            unsigned short* __restrict__ d2, unsigned short* __restrict__ d3) {
  int i = blockIdx.x * 256 + threadIdx.x;   // float4 index, total 4194304
  const float* s; unsigned short* d; int off;
  if (i < 786432)       { s = s0; d = d0; off = i; }
  else if (i < 1048576) { s = s1; d = d1; off = i - 786432; }
  else if (i < 3145728) { s = s2; d = d2; off = i - 1048576; }
  else                  { s = s3; d = d3; off = i - 3145728; }
  float4 v = ((const float4*)s)[off];
  ushort4 o;
  o.x = f2b(v.x); o.y = f2b(v.y); o.z = f2b(v.z); o.w = f2b(v.w);
  ((ushort4*)d)[off] = o;
}

// ---------------- conditioning: silu(c) @ {shift,scale}_w^T + b ----------------

__global__ void cond_kernel(const float* __restrict__ c,
                            const float* __restrict__ scale_w, const float* __restrict__ scale_b,
                            const float* __restrict__ shift_w, const float* __restrict__ shift_b,
                            float* __restrict__ scale_o, float* __restrict__ shift_o) {
  __shared__ float sc[1024];
  __shared__ float red[2][4][64];
  int tid = threadIdx.x;
  int b = blockIdx.x >> 4, ch = blockIdx.x & 15;
  for (int i = tid; i < 1024; i += 256) {
    float cv = c[b * 1024 + i];
    sc[i] = cv / (1.f + __expf(-cv));
  }
  __syncthreads();
  int colidx = tid & 63, p = tid >> 6;
  int co = ch * 64 + colidx;
  float dsc = 0.f, dsh = 0.f;
  for (int i = 0; i < 256; ++i) {
    int kk = p * 256 + i;
    float s = sc[kk];
    dsc += s * scale_w[(size_t)co * 1024 + kk];
    dsh += s * shift_w[(size_t)co * 1024 + kk];
  }
  red[0][p][colidx] = dsc;
  red[1][p][colidx] = dsh;
  __syncthreads();
  if (p == 0) {
    float s4  = red[0][0][colidx] + red[0][1][colidx] + red[0][2][colidx] + red[0][3][colidx];
    float sh4 = red[1][0][colidx] + red[1][1][colidx] + red[1][2][colidx] + red[1][3][colidx];
    scale_o[b * 1024 + co] = fminf(fmaxf(s4 + scale_b[co] + 1.f, 0.1f), 10.f);
    shift_o[b * 1024 + co] = sh4 + shift_b[co];
  }
}

// ---------------- adaLN ----------------

__global__ __launch_bounds__(256) void adaln_kernel(const float* __restrict__ x,
                                                    const float* __restrict__ norm_w,
                                                    const float* __restrict__ scale,
                                                    const float* __restrict__ shift,
                                                    unsigned short* __restrict__ h) {
  int row = blockIdx.x;
  int b = row >> 11;
  int tid = threadIdx.x;
  float4 v = ((const float4*)(x + (size_t)row * 1024))[tid];
  float ss = v.x * v.x + v.y * v.y + v.z * v.z + v.w * v.w;
  #pragma unroll
  for (int d = 32; d; d >>= 1) ss += __shfl_xor(ss, d);
  __shared__ float wsum[4];
  if ((tid & 63) == 0) wsum[tid >> 6] = ss;
  __syncthreads();
  float tot = wsum[0] + wsum[1] + wsum[2] + wsum[3];
  float inv = 1.f / fmaxf(sqrtf(tot * (1.f / 1024.f)), 1e-6f);
  float4 nw  = ((const float4*)norm_w)[tid];
  float4 scv = ((const float4*)(scale + b * 1024))[tid];
  float4 shv = ((const float4*)(shift + b * 1024))[tid];
  ushort4 o;
  o.x = f2b(v.x * inv * nw.x * scv.x + shv.x);
  o.y = f2b(v.y * inv * nw.y * scv.y + shv.y);
  o.z = f2b(v.z * inv * nw.z * scv.z + shv.z);
  o.w = f2b(v.w * inv * nw.w * scv.w + shv.w);
  ((ushort4*)(h + (size_t)row * 1024))[tid] = o;
}

// ---------------- 128x128 bf16 MFMA GEMM:  C = A[M,K] @ B[N,K]^T ----------------
// K-chunk XOR swizzle in global fetch; conflict-free fragment reads.
// EPI 0: out0(f32) = acc + bias0[col] + resid  (64B-per-quad f32 stores, full lines)
// EPI 1: QKV: stage tile in LDS -> coalesced 128B-row writes of q(x0.125),k [B,H,N,D]
//        and v [B,H,D,N] via in-LDS transpose.
// EPI 2: dual-B GLU -> stage -> coalesced 128B writes.

template<int EPI>
__global__ __launch_bounds__(256, 1) void gemm_k(
    const unsigned short* __restrict__ A,
    const unsigned short* __restrict__ B0,
    const unsigned short* __restrict__ B1,
    const float* __restrict__ bias0,
    const float* __restrict__ bias1,
    const float* __restrict__ resid,
    void* __restrict__ out0_, void* __restrict__ out1_, void* __restrict__ out2_,
    int M, int N, int K) {
  constexpr bool DUAL = (EPI == 2);
  constexpr int COMPUTE_SH = 4096 + 4096 + (DUAL ? 4096 : 8);
  constexpr int STAGE_SH = (EPI == 1 || EPI == 2) ? 128 * 136 : 0;
  constexpr int SMEM_SH = (COMPUTE_SH > STAGE_SH) ? COMPUTE_SH : STAGE_SH;
  __shared__ __align__(16) unsigned short smem[SMEM_SH];
  unsigned short* As  = smem;
  unsigned short* Bs  = smem + 4096;
  unsigned short* Bs2 = smem + 8192;

  const int tid = threadIdx.x;
  const int wave = tid >> 6, lane = tid & 63;
  const int quad = lane >> 4, l16 = lane & 15;
  const int wm = (wave >> 1) * 64, wn = (wave & 1) * 64;
  const int bm = blockIdx.y * 128, bn = blockIdx.x * 128;
  const int kx8 = (quad ^ (l16 & 3)) * 8;   // swizzled fragment k-chunk

  f32x4 acc[4][4] = {};
  f32x4 acc2[DUAL ? 4 : 1][DUAL ? 4 : 1] = {};

  const int steps = K >> 5;
  for (int s = 0; s < steps; ++s) {
    const int k0 = s << 5;
    __syncthreads();
    #pragma unroll
    for (int i = 0; i < 2; ++i) {
      int cc = i * 256 + tid;
      int r = cc >> 2;
      int ko = (((cc & 3) ^ (r & 3)) << 3);     // XOR swizzle in global fetch
      async16(As + (i * 2048 + wave * 512), A + ((size_t)(bm + r) * K + k0 + ko));
      async16(Bs + (i * 2048 + wave * 512), B0 + ((size_t)(bn + r) * K + k0 + ko));
      if constexpr (DUAL)
        async16(Bs2 + (i * 2048 + wave * 512), B1 + ((size_t)(bn + r) * K + k0 + ko));
    }
    __syncthreads();
    bf16x8 af[4], bfr[4];
    #pragma unroll
    for (int mi = 0; mi < 4; ++mi)
      af[mi] = *reinterpret_cast<const bf16x8*>(&As[(wm + mi * 16 + l16) * 32 + kx8]);
    #pragma unroll
    for (int ni = 0; ni < 4; ++ni)
      bfr[ni] = *reinterpret_cast<const bf16x8*>(&Bs[(wn + ni * 16 + l16) * 32 + kx8]);
    #pragma unroll
    for (int mi = 0; mi < 4; ++mi)
      #pragma unroll
      for (int ni = 0; ni < 4; ++ni)
        acc[mi][ni] = __builtin_amdgcn_mfma_f32_16x16x32_bf16(af[mi], bfr[ni], acc[mi][ni], 0, 0, 0);
    if constexpr (DUAL) {
      bf16x8 bg[4];
      #pragma unroll
      for (int ni = 0; ni < 4; ++ni)
        bg[ni] = *reinterpret_cast<const bf16x8*>(&Bs2[(wn + ni * 16 + l16) * 32 + kx8]);
      #pragma unroll
      for (int mi = 0; mi < 4; ++mi)
        #pragma unroll
        for (int ni = 0; ni < 4; ++ni)
          acc2[mi][ni] = __builtin_amdgcn_mfma_f32_16x16x32_bf16(af[mi], bg[ni], acc2[mi][ni], 0, 0, 0);
    }
  }

  // ---------- epilogue: C/D layout col=lane&15, row=quad*4+reg ----------
  if constexpr (EPI == 0) {
    #pragma unroll
    for (int mi = 0; mi < 4; ++mi) {
      #pragma unroll
      for (int ni = 0; ni < 4; ++ni) {
        int gc = bn + wn + ni * 16 + l16;
        #pragma unroll
        for (int r = 0; r < 4; ++r) {
          int gr = bm + wm + mi * 16 + quad * 4 + r;
          ((float*)out0_)[(size_t)gr * N + gc] = acc[mi][ni][r] + bias0[gc] + resid[(size_t)gr * N + gc];
        }
      }
    }
  } else if constexpr (EPI == 1) {
    const int region = bn >> 10;          // 0=q, 1=k, 2=v
    __syncthreads();                      // all waves done with As/Bs
    #pragma unroll
    for (int mi = 0; mi < 4; ++mi) {
      #pragma unroll
      for (int ni = 0; ni < 4; ++ni) {
        int lc = wn + ni * 16 + l16;
        #pragma unroll
        for (int r = 0; r < 4; ++r) {
          int lr = wm + mi * 16 + quad * 4 + r;
          float v = acc[mi][ni][r];
          if (region == 0)      smem[lr * 136 + lc] = f2b(v * 0.125f);
          else if (region == 1) smem[lr * 136 + lc] = f2b(v);
          else                  smem[lc * 136 + lr] = f2b(v);   // transpose for v
        }
      }
    }
    __syncthreads();
    const int b = bm >> 11;
    const int bnm = bn & 1023;
    if (region <= 1) {   // q or k: per (row, head-half) 128B contiguous
      int lr = tid >> 1, hl = tid & 1;
      int n = (bm + lr) & 2047;
      int hh = (bnm >> 6) + hl;
      unsigned short* dst = (unsigned short*)(region == 0 ? out0_ : out1_) +
                            (((size_t)(b * 16 + hh)) * 2048 + n) * 64;
      const unsigned short* src = smem + lr * 136 + hl * 64;
      #pragma unroll
      for (int j = 0; j < 8; ++j)
        ((uint4*)dst)[j] = *(const uint4*)(src + j * 8);
    } else {             // v: per (d, n-half) 128B contiguous
      int lc = tid >> 1, nh = tid & 1;
      int c2 = bnm + lc;
      int hh = c2 >> 6, d = c2 & 63;
      int nbase = (bm & 2047) + nh * 64;
      unsigned short* dst = (unsigned short*)out2_ +
                            (((size_t)(b * 16 + hh)) * 64 + d) * 2048 + nbase;
      const unsigned short* src = smem + lc * 136 + nh * 64;
      #pragma unroll
      for (int j = 0; j < 8; ++j)
        ((uint4*)dst)[j] = *(const uint4*)(src + j * 8);
    }
  } else {   // EPI 2: GLU -> stage -> coalesced
    __syncthreads();
    #pragma unroll
    for (int mi = 0; mi < 4; ++mi) {
      #pragma unroll
      for (int ni = 0; ni < 4; ++ni) {
        int gc = bn + wn + ni * 16 + l16;
        int lc = wn + ni * 16 + l16;
        #pragma unroll
        for (int r = 0; r < 4; ++r) {
          int lr = wm + mi * 16 + quad * 4 + r;
          float a  = acc[mi][ni][r] + bias0[gc];
          float b2 = acc2[mi][ni][r] + bias1[gc];
          smem[lr * 136 + lc] = f2b((a / (1.f + __expf(-a))) * b2);
        }
      }
    }
    __syncthreads();
    int lr = tid >> 1, hl = tid & 1;
    unsigned short* dst = (unsigned short*)out0_ + (size_t)(bm + lr) * N + bn + hl * 64;
    const unsigned short* src = smem + lr * 136 + hl * 64;
    #pragma unroll
    for (int j = 0; j < 8; ++j)
      ((uint4*)dst)[j] = *(const uint4*)(src + j * 8);
  }
}

// ---------------- flash attention (S^T formulation, Q-tile 128) ----------------
// q,k: [B,H,N,D] bf16 (q pre-scaled by 0.125); vt: [B,H,D,N] bf16
// grid (32 bh, 16 qt); block 256 = 4 waves x 32 q-rows (2 m-frags).
// Coalesced output via LDS stage (128B rows).

__global__ __launch_bounds__(256, 1) void attn_kernel(
    const unsigned short* __restrict__ q, const unsigned short* __restrict__ k,
    const unsigned short* __restrict__ vt, const int* __restrict__ amask,
    unsigned short* __restrict__ o) {
  const int bh = blockIdx.x;
  const int b = bh >> 4, h = bh & 15;
  const int qt = blockIdx.y;
  const int tid = threadIdx.x;
  const int wave = tid >> 6, lane = tid & 63;
  const int quad = lane >> 4, l16 = lane & 15;
  const int h7 = l16 & 7;
  const int kc0 = (quad ^ h7) * 8;
  const int kc1 = ((quad + 4) ^ h7) * 8;

  const unsigned short* qb = q  + (size_t)bh * 2048 * 64;
  const unsigned short* kb = k  + (size_t)bh * 2048 * 64;
  const unsigned short* vb = vt + (size_t)bh * 64 * 2048;

  __shared__ __align__(16) unsigned short Ks[64 * 64];
  __shared__ __align__(16) unsigned short Vs[64 * 64];
  __shared__ __align__(16) unsigned short Ps[4 * 2 * 16 * 72];  // also epilogue stage [128][72]
  __shared__ float biasf[64];

  unsigned short* Psm[2] = { Ps + wave * 2304, Ps + wave * 2304 + 1152 };

  bf16x8 qa[2][2];
  #pragma unroll
  for (int m = 0; m < 2; ++m) {
    int qrow = qt * 128 + wave * 32 + m * 16 + l16;
    qa[m][0] = *reinterpret_cast<const bf16x8*>(&qb[(size_t)qrow * 64 + quad * 8]);
    qa[m][1] = *reinterpret_cast<const bf16x8*>(&qb[(size_t)qrow * 64 + 32 + quad * 8]);
  }

  f32x4 oacc[2][4] = {};
  float mrow[2] = {-30000.f, -30000.f}, lrow[2] = {0.f, 0.f};

  // prefetch tile 0
  uint4 kpre[2], vpre[2];
  #pragma unroll
  for (int i = 0; i < 2; ++i) {
    int cc = i * 256 + tid;
    int key = cc >> 3, dl = (cc & 7) ^ (key & 7);
    kpre[i] = *(const uint4*)(kb + key * 64 + dl * 8);
    int d = cc >> 3, kl = (cc & 7) ^ (d & 7);
    vpre[i] = *(const uint4*)(vb + (size_t)d * 2048 + kl * 8);
  }
  int mv = (tid < 64) ? amask[b * 2048 + tid] : 0;

  for (int kt = 0; kt < 32; ++kt) {
    __syncthreads();
    ((uint4*)Ks)[tid]       = kpre[0];
    ((uint4*)Ks)[256 + tid] = kpre[1];
    ((uint4*)Vs)[tid]       = vpre[0];
    ((uint4*)Vs)[256 + tid] = vpre[1];
    if (tid < 64) biasf[tid] = mv ? 0.f : -30000.f;
    __syncthreads();

    if (kt + 1 < 32) {
      #pragma unroll
      for (int i = 0; i < 2; ++i) {
        int cc = i * 256 + tid;
        int key = cc >> 3, dl = (cc & 7) ^ (key & 7);
        kpre[i] = *(const uint4*)(kb + (size_t)(kt + 1) * 4096 + key * 64 + dl * 8);
        int d = cc >> 3, kl = (cc & 7) ^ (d & 7);
        vpre[i] = *(const uint4*)(vb + (size_t)d * 2048 + (kt + 1) * 64 + kl * 8);
      }
      mv = (tid < 64) ? amask[b * 2048 + (kt + 1) * 64 + tid] : 0;
    }

    // S^T: lane holds S[q=l16][key=nt*16+quad*4+r] per m-frag
    f32x4 st[2][4];
    #pragma unroll
    for (int nt = 0; nt < 4; ++nt) {
      bf16x8 ka0 = *reinterpret_cast<const bf16x8*>(&Ks[(nt * 16 + l16) * 64 + kc0]);
      bf16x8 ka1 = *reinterpret_cast<const bf16x8*>(&Ks[(nt * 16 + l16) * 64 + kc1]);
      f32x4 bv = *reinterpret_cast<const f32x4*>(&biasf[nt * 16 + quad * 4]);
      #pragma unroll
      for (int m = 0; m < 2; ++m) {
        f32x4 z = {};
        z = __builtin_amdgcn_mfma_f32_16x16x32_bf16(ka0, qa[m][0], z, 0, 0, 0);
        z = __builtin_amdgcn_mfma_f32_16x16x32_bf16(ka1, qa[m][1], z, 0, 0, 0);
        st[m][nt] = z + bv;
      }
    }

    #pragma unroll
    for (int m = 0; m < 2; ++m) {
      float tm = -1e30f;
      #pragma unroll
      for (int nt = 0; nt < 4; ++nt)
        #pragma unroll
        for (int r = 0; r < 4; ++r) tm = fmaxf(tm, st[m][nt][r]);
      tm = fmaxf(tm, __shfl_xor(tm, 16));
      tm = fmaxf(tm, __shfl_xor(tm, 32));

      float mnew = fmaxf(mrow[m], tm);
      float alpha = __expf(mrow[m] - mnew);
      mrow[m] = mnew;

      float rs = 0.f;
      #pragma unroll
      for (int nt = 0; nt < 4; ++nt) {
        float p0 = __expf(st[m][nt][0] - mnew);
        float p1 = __expf(st[m][nt][1] - mnew);
        float p2 = __expf(st[m][nt][2] - mnew);
        float p3 = __expf(st[m][nt][3] - mnew);
        rs += (p0 + p1) + (p2 + p3);
        uint2 w;
        w.x = packtrunc(p0, p1);
        w.y = packtrunc(p2, p3);
        *(uint2*)&Psm[m][l16 * 72 + nt * 16 + quad * 4] = w;
      }
      rs += __shfl_xor(rs, 16);
      rs += __shfl_xor(rs, 32);
      lrow[m] = lrow[m] * alpha + rs;

      float a0 = __shfl(alpha, quad * 4 + 0);
      float a1 = __shfl(alpha, quad * 4 + 1);
      float a2 = __shfl(alpha, quad * 4 + 2);
      float a3 = __shfl(alpha, quad * 4 + 3);
      #pragma unroll
      for (int dt = 0; dt < 4; ++dt) {
        oacc[m][dt][0] *= a0; oacc[m][dt][1] *= a1;
        oacc[m][dt][2] *= a2; oacc[m][dt][3] *= a3;
      }
    }

    bf16x8 pa[2][2];
    #pragma unroll
    for (int m = 0; m < 2; ++m) {
      pa[m][0] = *reinterpret_cast<const bf16x8*>(&Psm[m][l16 * 72 + quad * 8]);
      pa[m][1] = *reinterpret_cast<const bf16x8*>(&Psm[m][l16 * 72 + 32 + quad * 8]);
    }
    #pragma unroll
    for (int dt = 0; dt < 4; ++dt) {
      bf16x8 vb0 = *reinterpret_cast<const bf16x8*>(&Vs[(dt * 16 + l16) * 64 + kc0]);
      bf16x8 vb1 = *reinterpret_cast<const bf16x8*>(&Vs[(dt * 16 + l16) * 64 + kc1]);
      #pragma unroll
      for (int m = 0; m < 2; ++m) {
        oacc[m][dt] = __builtin_amdgcn_mfma_f32_16x16x32_bf16(pa[m][0], vb0, oacc[m][dt], 0, 0, 0);
        oacc[m][dt] = __builtin_amdgcn_mfma_f32_16x16x32_bf16(pa[m][1], vb1, oacc[m][dt], 0, 0, 0);
      }
    }
  }

  // epilogue: normalize, stage to LDS, coalesced 128B-row writes
  float iv[2][4];
  #pragma unroll
  for (int m = 0; m < 2; ++m) {
    float invl = lrow[m] > 0.f ? 1.f / lrow[m] : 0.f;
    #pragma unroll
    for (int r = 0; r < 4; ++r) iv[m][r] = __shfl(invl, quad * 4 + r);
  }
  __syncthreads();   // all waves done with Ps before reuse as stage
  #pragma unroll
  for (int m = 0; m < 2; ++m)
    #pragma unroll
    for (int dt = 0; dt < 4; ++dt)
      #pragma unroll
      for (int r = 0; r < 4; ++r) {
        int lr = wave * 32 + m * 16 + quad * 4 + r;
        Ps[lr * 72 + dt * 16 + l16] = f2b(oacc[m][dt][r] * iv[m][r]);
      }
  __syncthreads();
  {
    int lr = tid >> 1, cb = (tid & 1) * 32;
    int n = qt * 128 + lr;
    unsigned short* dst = o + ((size_t)(b * 2048 + n)) * 1024 + h * 64 + cb;
    const unsigned short* src = Ps + lr * 72 + cb;
    #pragma unroll
    for (int j = 0; j < 4; ++j)
      ((uint4*)dst)[j] = *(const uint4*)(src + j * 8);
  }
}

// ---------------- launch ----------------

extern "C" void kernel_launch(void* const* d_in, const int* in_sizes, int n_in,
                              void* d_out, int out_size, void* d_ws, size_t ws_size,
                              hipStream_t stream) {
  const float* x       = (const float*)d_in[0];
  const float* c       = (const float*)d_in[1];
  const int*   amask   = (const int*)d_in[2];
  const float* norm_w  = (const float*)d_in[3];
  const float* scale_w = (const float*)d_in[4];
  const float* scale_b = (const float*)d_in[5];
  const float* shift_w = (const float*)d_in[6];
  const float* shift_b = (const float*)d_in[7];
  const float* qkv_w   = (const float*)d_in[8];
  const float* proj_w  = (const float*)d_in[9];
  const float* proj_b  = (const float*)d_in[10];
  const float* mlp_w1  = (const float*)d_in[11];
  const float* mlp_b1  = (const float*)d_in[12];
  const float* mlp_w2  = (const float*)d_in[13];
  const float* mlp_b2  = (const float*)d_in[14];

  char* ws = (char*)d_ws;
  unsigned short* wqkv  = (unsigned short*)(ws + 0);
  unsigned short* wproj = (unsigned short*)(ws + 6291456);
  unsigned short* wmlp1 = (unsigned short*)(ws + 8388608);
  unsigned short* wmlp2 = (unsigned short*)(ws + 25165824);
  float* scale_o        = (float*)(ws + 33554432);
  float* shift_o        = (float*)(ws + 33562624);
  unsigned short* hbuf  = (unsigned short*)(ws + 33570816);
  unsigned short* qbuf  = (unsigned short*)(ws + 41959424);
  unsigned short* kbuf  = (unsigned short*)(ws + 50348032);
  unsigned short* vbuf  = (unsigned short*)(ws + 58736640);
  unsigned short* abuf  = (unsigned short*)(ws + 67125248);
  unsigned short* gbuf  = qbuf;
  float* x1             = (float*)(ws + 75513856);

  cvt4_kernel<<<16384, 256, 0, stream>>>(qkv_w, proj_w, mlp_w1, mlp_w2,
                                         wqkv, wproj, wmlp1, wmlp2);

  cond_kernel<<<32, 256, 0, stream>>>(c, scale_w, scale_b, shift_w, shift_b, scale_o, shift_o);

  adaln_kernel<<<4096, 256, 0, stream>>>(x, norm_w, scale_o, shift_o, hbuf);

  gemm_k<1><<<dim3(24, 32), 256, 0, stream>>>(hbuf, wqkv, nullptr, nullptr, nullptr, nullptr,
                                              qbuf, kbuf, vbuf, 4096, 3072, 1024);

  attn_kernel<<<dim3(32, 16), 256, 0, stream>>>(qbuf, kbuf, vbuf, amask, abuf);

  gemm_k<0><<<dim3(8, 32), 256, 0, stream>>>(abuf, wproj, nullptr, proj_b, nullptr, x,
                                             x1, nullptr, nullptr, 4096, 1024, 1024);

  adaln_kernel<<<4096, 256, 0, stream>>>(x1, norm_w, scale_o, shift_o, hbuf);

  gemm_k<2><<<dim3(32, 32), 256, 0, stream>>>(hbuf, wmlp1, wmlp1 + 4096 * 1024, mlp_b1, mlp_b1 + 4096,
                                              nullptr, gbuf, nullptr, nullptr, 4096, 4096, 1024);

  gemm_k<0><<<dim3(8, 32), 256, 0, stream>>>(gbuf, wmlp2, nullptr, mlp_b2, nullptr, x1,
                                             d_out, nullptr, nullptr, 4096, 1024, 4096);

  (void)in_sizes; (void)n_in; (void)out_size; (void)ws_size;
}

// Round 4
// 552.542 us; speedup vs baseline: 1.1950x; 1.0976x over previous
//
#include <hip/hip_runtime.h>
#include <cstdint>
#include <cstddef>

#define DEVINL __device__ __forceinline__

typedef __bf16 bf16x8 __attribute__((ext_vector_type(8)));
typedef float  f32x4  __attribute__((ext_vector_type(4)));

// ---------------- helpers ----------------

DEVINL unsigned short f2b(float f) {   // f32 -> bf16 bits, round-to-nearest-even
  unsigned u = __builtin_bit_cast(unsigned, f);
  u += 0x7fffu + ((u >> 16) & 1u);
  return (unsigned short)(u >> 16);
}

DEVINL unsigned packtrunc(float a, float b) {  // 2x f32 -> packed bf16 (truncate)
  unsigned ua = __builtin_bit_cast(unsigned, a);
  unsigned ub = __builtin_bit_cast(unsigned, b);
  return (ua >> 16) | (ub & 0xffff0000u);
}

DEVINL void async16(void* lds, const void* g) {
  __builtin_amdgcn_global_load_lds((const __attribute__((address_space(1))) unsigned*)g,
                                   (__attribute__((address_space(3))) unsigned*)lds,
                                   16, 0, 0);
}

// ---------------- fused weight f32 -> bf16 cast (all 4 weights, 1 launch) ----------------
// mlp_w1 (s2) rows are INTERLEAVED on write: gate row i -> 2i, up row i -> 2i+1,
// so the MLP1 GEMM sees gate/up pairs in adjacent output columns (GLU via shfl_xor(1)).

__global__ void cvt4_kernel(const float* __restrict__ s0, const float* __restrict__ s1,
                            const float* __restrict__ s2, const float* __restrict__ s3,
                            unsigned short* __restrict__ d0, unsigned short* __restrict__ d1,
                            unsigned short* __restrict__ d2, unsigned short* __restrict__ d3) {
  int i = blockIdx.x * 256 + threadIdx.x;   // float4 index, total 4194304
  if (i < 786432) {
    float4 v = ((const float4*)s0)[i];
    ushort4 o; o.x = f2b(v.x); o.y = f2b(v.y); o.z = f2b(v.z); o.w = f2b(v.w);
    ((ushort4*)d0)[i] = o;
  } else if (i < 1048576) {
    int off = i - 786432;
    float4 v = ((const float4*)s1)[off];
    ushort4 o; o.x = f2b(v.x); o.y = f2b(v.y); o.z = f2b(v.z); o.w = f2b(v.w);
    ((ushort4*)d1)[off] = o;
  } else if (i < 3145728) {
    int off = i - 1048576;                  // mlp_w1: 8192 rows x 256 float4
    int row = off >> 8, col = off & 255;
    int rp = (row < 4096) ? (row << 1) : (((row - 4096) << 1) | 1);
    float4 v = ((const float4*)s2)[off];
    ushort4 o; o.x = f2b(v.x); o.y = f2b(v.y); o.z = f2b(v.z); o.w = f2b(v.w);
    ((ushort4*)d2)[rp * 256 + col] = o;
  } else {
    int off = i - 3145728;
    float4 v = ((const float4*)s3)[off];
    ushort4 o; o.x = f2b(v.x); o.y = f2b(v.y); o.z = f2b(v.z); o.w = f2b(v.w);
    ((ushort4*)d3)[off] = o;
  }
}

// ---------------- conditioning: silu(c) @ {shift,scale}_w^T + b ----------------

__global__ void cond_kernel(const float* __restrict__ c,
                            const float* __restrict__ scale_w, const float* __restrict__ scale_b,
                            const float* __restrict__ shift_w, const float* __restrict__ shift_b,
                            float* __restrict__ scale_o, float* __restrict__ shift_o) {
  __shared__ float sc[1024];
  __shared__ float red[2][4][64];
  int tid = threadIdx.x;
  int b = blockIdx.x >> 4, ch = blockIdx.x & 15;
  for (int i = tid; i < 1024; i += 256) {
    float cv = c[b * 1024 + i];
    sc[i] = cv / (1.f + __expf(-cv));
  }
  __syncthreads();
  int colidx = tid & 63, p = tid >> 6;
  int co = ch * 64 + colidx;
  float dsc = 0.f, dsh = 0.f;
  for (int i = 0; i < 256; ++i) {
    int kk = p * 256 + i;
    float s = sc[kk];
    dsc += s * scale_w[(size_t)co * 1024 + kk];
    dsh += s * shift_w[(size_t)co * 1024 + kk];
  }
  red[0][p][colidx] = dsc;
  red[1][p][colidx] = dsh;
  __syncthreads();
  if (p == 0) {
    float s4  = red[0][0][colidx] + red[0][1][colidx] + red[0][2][colidx] + red[0][3][colidx];
    float sh4 = red[1][0][colidx] + red[1][1][colidx] + red[1][2][colidx] + red[1][3][colidx];
    scale_o[b * 1024 + co] = fminf(fmaxf(s4 + scale_b[co] + 1.f, 0.1f), 10.f);
    shift_o[b * 1024 + co] = sh4 + shift_b[co];
  }
}

// ---------------- adaLN ----------------

__global__ __launch_bounds__(256) void adaln_kernel(const float* __restrict__ x,
                                                    const float* __restrict__ norm_w,
                                                    const float* __restrict__ scale,
                                                    const float* __restrict__ shift,
                                                    unsigned short* __restrict__ h) {
  int row = blockIdx.x;
  int b = row >> 11;
  int tid = threadIdx.x;
  float4 v = ((const float4*)(x + (size_t)row * 1024))[tid];
  float ss = v.x * v.x + v.y * v.y + v.z * v.z + v.w * v.w;
  #pragma unroll
  for (int d = 32; d; d >>= 1) ss += __shfl_xor(ss, d);
  __shared__ float wsum[4];
  if ((tid & 63) == 0) wsum[tid >> 6] = ss;
  __syncthreads();
  float tot = wsum[0] + wsum[1] + wsum[2] + wsum[3];
  float inv = 1.f / fmaxf(sqrtf(tot * (1.f / 1024.f)), 1e-6f);
  float4 nw  = ((const float4*)norm_w)[tid];
  float4 scv = ((const float4*)(scale + b * 1024))[tid];
  float4 shv = ((const float4*)(shift + b * 1024))[tid];
  ushort4 o;
  o.x = f2b(v.x * inv * nw.x * scv.x + shv.x);
  o.y = f2b(v.y * inv * nw.y * scv.y + shv.y);
  o.z = f2b(v.z * inv * nw.z * scv.z + shv.z);
  o.w = f2b(v.w * inv * nw.w * scv.w + shv.w);
  ((ushort4*)(h + (size_t)row * 1024))[tid] = o;
}

// ---------------- 128x128 bf16 MFMA GEMM:  C = A[M,K] @ B[N,K]^T ----------------
// Single accumulator (64 AGPR) for ALL epilogues -> ~2 waves/SIMD occupancy.
// EPI 0: out0(f32) = acc + bias0[col] + resid
// EPI 1: QKV: stage tile in LDS -> coalesced writes q(x0.125),k [B,H,N,D]; v [B,H,D,N]
// EPI 2: interleaved GLU (B rows pre-interleaved gate/up): pair via shfl_xor(1),
//        g = silu(gate+bg)*(up+bu) -> bf16 out [M, N/2], staged coalesced.

template<int EPI>
__global__ __launch_bounds__(256, 1) void gemm_k(
    const unsigned short* __restrict__ A,
    const unsigned short* __restrict__ B0,
    const float* __restrict__ bias0,
    const float* __restrict__ resid,
    void* __restrict__ out0_, void* __restrict__ out1_, void* __restrict__ out2_,
    int M, int N, int K) {
  constexpr int COMPUTE_SH = 4096 + 4096;
  constexpr int STAGE_SH = (EPI == 1) ? 128 * 136 : (EPI == 2 ? 128 * 72 : 0);
  constexpr int SMEM_SH = (COMPUTE_SH > STAGE_SH) ? COMPUTE_SH : STAGE_SH;
  __shared__ __align__(16) unsigned short smem[SMEM_SH];
  unsigned short* As  = smem;
  unsigned short* Bs  = smem + 4096;

  const int tid = threadIdx.x;
  const int wave = tid >> 6, lane = tid & 63;
  const int quad = lane >> 4, l16 = lane & 15;
  const int wm = (wave >> 1) * 64, wn = (wave & 1) * 64;
  const int bm = blockIdx.y * 128, bn = blockIdx.x * 128;
  const int kx8 = (quad ^ (l16 & 3)) * 8;   // swizzled fragment k-chunk

  f32x4 acc[4][4] = {};

  const int steps = K >> 5;
  for (int s = 0; s < steps; ++s) {
    const int k0 = s << 5;
    __syncthreads();
    #pragma unroll
    for (int i = 0; i < 2; ++i) {
      int cc = i * 256 + tid;
      int r = cc >> 2;
      int ko = (((cc & 3) ^ (r & 3)) << 3);     // XOR swizzle in global fetch
      async16(As + (i * 2048 + wave * 512), A + ((size_t)(bm + r) * K + k0 + ko));
      async16(Bs + (i * 2048 + wave * 512), B0 + ((size_t)(bn + r) * K + k0 + ko));
    }
    __syncthreads();
    bf16x8 af[4], bfr[4];
    #pragma unroll
    for (int mi = 0; mi < 4; ++mi)
      af[mi] = *reinterpret_cast<const bf16x8*>(&As[(wm + mi * 16 + l16) * 32 + kx8]);
    #pragma unroll
    for (int ni = 0; ni < 4; ++ni)
      bfr[ni] = *reinterpret_cast<const bf16x8*>(&Bs[(wn + ni * 16 + l16) * 32 + kx8]);
    #pragma unroll
    for (int mi = 0; mi < 4; ++mi)
      #pragma unroll
      for (int ni = 0; ni < 4; ++ni)
        acc[mi][ni] = __builtin_amdgcn_mfma_f32_16x16x32_bf16(af[mi], bfr[ni], acc[mi][ni], 0, 0, 0);
  }

  // ---------- epilogue: C/D layout col=lane&15, row=quad*4+reg ----------
  if constexpr (EPI == 0) {
    #pragma unroll
    for (int mi = 0; mi < 4; ++mi) {
      #pragma unroll
      for (int ni = 0; ni < 4; ++ni) {
        int gc = bn + wn + ni * 16 + l16;
        #pragma unroll
        for (int r = 0; r < 4; ++r) {
          int gr = bm + wm + mi * 16 + quad * 4 + r;
          ((float*)out0_)[(size_t)gr * N + gc] = acc[mi][ni][r] + bias0[gc] + resid[(size_t)gr * N + gc];
        }
      }
    }
  } else if constexpr (EPI == 1) {
    const int region = bn >> 10;          // 0=q, 1=k, 2=v
    __syncthreads();                      // all waves done with As/Bs
    #pragma unroll
    for (int mi = 0; mi < 4; ++mi) {
      #pragma unroll
      for (int ni = 0; ni < 4; ++ni) {
        int lc = wn + ni * 16 + l16;
        #pragma unroll
        for (int r = 0; r < 4; ++r) {
          int lr = wm + mi * 16 + quad * 4 + r;
          float v = acc[mi][ni][r];
          if (region == 0)      smem[lr * 136 + lc] = f2b(v * 0.125f);
          else if (region == 1) smem[lr * 136 + lc] = f2b(v);
          else                  smem[lc * 136 + lr] = f2b(v);   // transpose for v
        }
      }
    }
    __syncthreads();
    const int b = bm >> 11;
    const int bnm = bn & 1023;
    if (region <= 1) {   // q or k: per (row, head-half) 128B contiguous
      int lr = tid >> 1, hl = tid & 1;
      int n = (bm + lr) & 2047;
      int hh = (bnm >> 6) + hl;
      unsigned short* dst = (unsigned short*)(region == 0 ? out0_ : out1_) +
                            (((size_t)(b * 16 + hh)) * 2048 + n) * 64;
      const unsigned short* src = smem + lr * 136 + hl * 64;
      #pragma unroll
      for (int j = 0; j < 8; ++j)
        ((uint4*)dst)[j] = *(const uint4*)(src + j * 8);
    } else {             // v: per (d, n-half) 128B contiguous
      int lc = tid >> 1, nh = tid & 1;
      int c2 = bnm + lc;
      int hh = c2 >> 6, d = c2 & 63;
      int nbase = (bm & 2047) + nh * 64;
      unsigned short* dst = (unsigned short*)out2_ +
                            (((size_t)(b * 16 + hh)) * 64 + d) * 2048 + nbase;
      const unsigned short* src = smem + lc * 136 + nh * 64;
      #pragma unroll
      for (int j = 0; j < 8; ++j)
        ((uint4*)dst)[j] = *(const uint4*)(src + j * 8);
    }
  } else {   // EPI 2: interleaved GLU -> bf16 [M, N/2]
    __syncthreads();
    #pragma unroll
    for (int mi = 0; mi < 4; ++mi) {
      #pragma unroll
      for (int ni = 0; ni < 4; ++ni) {
        int lc = wn + ni * 16 + l16;
        int gcp = bn + lc;                 // interleaved col
        int gi = gcp >> 1;                 // logical GLU index
        float bias = bias0[(gcp & 1) ? 4096 + gi : gi];
        #pragma unroll
        for (int r = 0; r < 4; ++r) {
          int lr = wm + mi * 16 + quad * 4 + r;
          float v = acc[mi][ni][r] + bias;
          float p = __shfl_xor(v, 1);      // partner: gate<->up (adjacent l16)
          if ((l16 & 1) == 0) {
            float g = (v / (1.f + __expf(-v))) * p;
            smem[lr * 72 + (lc >> 1)] = f2b(g);
          }
        }
      }
    }
    __syncthreads();
    int lr = tid >> 1, ch = (tid & 1) * 32;
    unsigned short* dst = (unsigned short*)out0_ + (size_t)(bm + lr) * (N >> 1) + (bn >> 1) + ch;
    const unsigned short* src = smem + lr * 72 + ch;
    #pragma unroll
    for (int j = 0; j < 4; ++j)
      ((uint4*)dst)[j] = *(const uint4*)(src + j * 8);
  }
}

// ---------------- flash attention (S^T formulation, Q-tile 128) ----------------

__global__ __launch_bounds__(256, 1) void attn_kernel(
    const unsigned short* __restrict__ q, const unsigned short* __restrict__ k,
    const unsigned short* __restrict__ vt, const int* __restrict__ amask,
    unsigned short* __restrict__ o) {
  const int bh = blockIdx.x;
  const int b = bh >> 4, h = bh & 15;
  const int qt = blockIdx.y;
  const int tid = threadIdx.x;
  const int wave = tid >> 6, lane = tid & 63;
  const int quad = lane >> 4, l16 = lane & 15;
  const int h7 = l16 & 7;
  const int kc0 = (quad ^ h7) * 8;
  const int kc1 = ((quad + 4) ^ h7) * 8;

  const unsigned short* qb = q  + (size_t)bh * 2048 * 64;
  const unsigned short* kb = k  + (size_t)bh * 2048 * 64;
  const unsigned short* vb = vt + (size_t)bh * 64 * 2048;

  __shared__ __align__(16) unsigned short Ks[64 * 64];
  __shared__ __align__(16) unsigned short Vs[64 * 64];
  __shared__ __align__(16) unsigned short Ps[4 * 2 * 16 * 72];  // also epilogue stage
  __shared__ float biasf[64];

  unsigned short* Psm[2] = { Ps + wave * 2304, Ps + wave * 2304 + 1152 };

  bf16x8 qa[2][2];
  #pragma unroll
  for (int m = 0; m < 2; ++m) {
    int qrow = qt * 128 + wave * 32 + m * 16 + l16;
    qa[m][0] = *reinterpret_cast<const bf16x8*>(&qb[(size_t)qrow * 64 + quad * 8]);
    qa[m][1] = *reinterpret_cast<const bf16x8*>(&qb[(size_t)qrow * 64 + 32 + quad * 8]);
  }

  f32x4 oacc[2][4] = {};
  float mrow[2] = {-30000.f, -30000.f}, lrow[2] = {0.f, 0.f};

  uint4 kpre[2], vpre[2];
  #pragma unroll
  for (int i = 0; i < 2; ++i) {
    int cc = i * 256 + tid;
    int key = cc >> 3, dl = (cc & 7) ^ (key & 7);
    kpre[i] = *(const uint4*)(kb + key * 64 + dl * 8);
    int d = cc >> 3, kl = (cc & 7) ^ (d & 7);
    vpre[i] = *(const uint4*)(vb + (size_t)d * 2048 + kl * 8);
  }
  int mv = (tid < 64) ? amask[b * 2048 + tid] : 0;

  for (int kt = 0; kt < 32; ++kt) {
    __syncthreads();
    ((uint4*)Ks)[tid]       = kpre[0];
    ((uint4*)Ks)[256 + tid] = kpre[1];
    ((uint4*)Vs)[tid]       = vpre[0];
    ((uint4*)Vs)[256 + tid] = vpre[1];
    if (tid < 64) biasf[tid] = mv ? 0.f : -30000.f;
    __syncthreads();

    if (kt + 1 < 32) {
      #pragma unroll
      for (int i = 0; i < 2; ++i) {
        int cc = i * 256 + tid;
        int key = cc >> 3, dl = (cc & 7) ^ (key & 7);
        kpre[i] = *(const uint4*)(kb + (size_t)(kt + 1) * 4096 + key * 64 + dl * 8);
        int d = cc >> 3, kl = (cc & 7) ^ (d & 7);
        vpre[i] = *(const uint4*)(vb + (size_t)d * 2048 + (kt + 1) * 64 + kl * 8);
      }
      mv = (tid < 64) ? amask[b * 2048 + (kt + 1) * 64 + tid] : 0;
    }

    f32x4 st[2][4];
    #pragma unroll
    for (int nt = 0; nt < 4; ++nt) {
      bf16x8 ka0 = *reinterpret_cast<const bf16x8*>(&Ks[(nt * 16 + l16) * 64 + kc0]);
      bf16x8 ka1 = *reinterpret_cast<const bf16x8*>(&Ks[(nt * 16 + l16) * 64 + kc1]);
      f32x4 bv = *reinterpret_cast<const f32x4*>(&biasf[nt * 16 + quad * 4]);
      #pragma unroll
      for (int m = 0; m < 2; ++m) {
        f32x4 z = {};
        z = __builtin_amdgcn_mfma_f32_16x16x32_bf16(ka0, qa[m][0], z, 0, 0, 0);
        z = __builtin_amdgcn_mfma_f32_16x16x32_bf16(ka1, qa[m][1], z, 0, 0, 0);
        st[m][nt] = z + bv;
      }
    }

    #pragma unroll
    for (int m = 0; m < 2; ++m) {
      float tm = -1e30f;
      #pragma unroll
      for (int nt = 0; nt < 4; ++nt)
        #pragma unroll
        for (int r = 0; r < 4; ++r) tm = fmaxf(tm, st[m][nt][r]);
      tm = fmaxf(tm, __shfl_xor(tm, 16));
      tm = fmaxf(tm, __shfl_xor(tm, 32));

      float mnew = fmaxf(mrow[m], tm);
      float alpha = __expf(mrow[m] - mnew);
      mrow[m] = mnew;

      float rs = 0.f;
      #pragma unroll
      for (int nt = 0; nt < 4; ++nt) {
        float p0 = __expf(st[m][nt][0] - mnew);
        float p1 = __expf(st[m][nt][1] - mnew);
        float p2 = __expf(st[m][nt][2] - mnew);
        float p3 = __expf(st[m][nt][3] - mnew);
        rs += (p0 + p1) + (p2 + p3);
        uint2 w;
        w.x = packtrunc(p0, p1);
        w.y = packtrunc(p2, p3);
        *(uint2*)&Psm[m][l16 * 72 + nt * 16 + quad * 4] = w;
      }
      rs += __shfl_xor(rs, 16);
      rs += __shfl_xor(rs, 32);
      lrow[m] = lrow[m] * alpha + rs;

      float a0 = __shfl(alpha, quad * 4 + 0);
      float a1 = __shfl(alpha, quad * 4 + 1);
      float a2 = __shfl(alpha, quad * 4 + 2);
      float a3 = __shfl(alpha, quad * 4 + 3);
      #pragma unroll
      for (int dt = 0; dt < 4; ++dt) {
        oacc[m][dt][0] *= a0; oacc[m][dt][1] *= a1;
        oacc[m][dt][2] *= a2; oacc[m][dt][3] *= a3;
      }
    }

    bf16x8 pa[2][2];
    #pragma unroll
    for (int m = 0; m < 2; ++m) {
      pa[m][0] = *reinterpret_cast<const bf16x8*>(&Psm[m][l16 * 72 + quad * 8]);
      pa[m][1] = *reinterpret_cast<const bf16x8*>(&Psm[m][l16 * 72 + 32 + quad * 8]);
    }
    #pragma unroll
    for (int dt = 0; dt < 4; ++dt) {
      bf16x8 vb0 = *reinterpret_cast<const bf16x8*>(&Vs[(dt * 16 + l16) * 64 + kc0]);
      bf16x8 vb1 = *reinterpret_cast<const bf16x8*>(&Vs[(dt * 16 + l16) * 64 + kc1]);
      #pragma unroll
      for (int m = 0; m < 2; ++m) {
        oacc[m][dt] = __builtin_amdgcn_mfma_f32_16x16x32_bf16(pa[m][0], vb0, oacc[m][dt], 0, 0, 0);
        oacc[m][dt] = __builtin_amdgcn_mfma_f32_16x16x32_bf16(pa[m][1], vb1, oacc[m][dt], 0, 0, 0);
      }
    }
  }

  float iv[2][4];
  #pragma unroll
  for (int m = 0; m < 2; ++m) {
    float invl = lrow[m] > 0.f ? 1.f / lrow[m] : 0.f;
    #pragma unroll
    for (int r = 0; r < 4; ++r) iv[m][r] = __shfl(invl, quad * 4 + r);
  }
  __syncthreads();
  #pragma unroll
  for (int m = 0; m < 2; ++m)
    #pragma unroll
    for (int dt = 0; dt < 4; ++dt)
      #pragma unroll
      for (int r = 0; r < 4; ++r) {
        int lr = wave * 32 + m * 16 + quad * 4 + r;
        Ps[lr * 72 + dt * 16 + l16] = f2b(oacc[m][dt][r] * iv[m][r]);
      }
  __syncthreads();
  {
    int lr = tid >> 1, cb = (tid & 1) * 32;
    int n = qt * 128 + lr;
    unsigned short* dst = o + ((size_t)(b * 2048 + n)) * 1024 + h * 64 + cb;
    const unsigned short* src = Ps + lr * 72 + cb;
    #pragma unroll
    for (int j = 0; j < 4; ++j)
      ((uint4*)dst)[j] = *(const uint4*)(src + j * 8);
  }
}

// ---------------- launch ----------------

extern "C" void kernel_launch(void* const* d_in, const int* in_sizes, int n_in,
                              void* d_out, int out_size, void* d_ws, size_t ws_size,
                              hipStream_t stream) {
  const float* x       = (const float*)d_in[0];
  const float* c       = (const float*)d_in[1];
  const int*   amask   = (const int*)d_in[2];
  const float* norm_w  = (const float*)d_in[3];
  const float* scale_w = (const float*)d_in[4];
  const float* scale_b = (const float*)d_in[5];
  const float* shift_w = (const float*)d_in[6];
  const float* shift_b = (const float*)d_in[7];
  const float* qkv_w   = (const float*)d_in[8];
  const float* proj_w  = (const float*)d_in[9];
  const float* proj_b  = (const float*)d_in[10];
  const float* mlp_w1  = (const float*)d_in[11];
  const float* mlp_b1  = (const float*)d_in[12];
  const float* mlp_w2  = (const float*)d_in[13];
  const float* mlp_b2  = (const float*)d_in[14];

  char* ws = (char*)d_ws;
  unsigned short* wqkv  = (unsigned short*)(ws + 0);
  unsigned short* wproj = (unsigned short*)(ws + 6291456);
  unsigned short* wmlp1 = (unsigned short*)(ws + 8388608);   // interleaved gate/up rows
  unsigned short* wmlp2 = (unsigned short*)(ws + 25165824);
  float* scale_o        = (float*)(ws + 33554432);
  float* shift_o        = (float*)(ws + 33562624);
  unsigned short* hbuf  = (unsigned short*)(ws + 33570816);
  unsigned short* qbuf  = (unsigned short*)(ws + 41959424);
  unsigned short* kbuf  = (unsigned short*)(ws + 50348032);
  unsigned short* vbuf  = (unsigned short*)(ws + 58736640);
  unsigned short* abuf  = (unsigned short*)(ws + 67125248);
  unsigned short* gbuf  = qbuf;
  float* x1             = (float*)(ws + 75513856);

  cvt4_kernel<<<16384, 256, 0, stream>>>(qkv_w, proj_w, mlp_w1, mlp_w2,
                                         wqkv, wproj, wmlp1, wmlp2);

  cond_kernel<<<32, 256, 0, stream>>>(c, scale_w, scale_b, shift_w, shift_b, scale_o, shift_o);

  adaln_kernel<<<4096, 256, 0, stream>>>(x, norm_w, scale_o, shift_o, hbuf);

  gemm_k<1><<<dim3(24, 32), 256, 0, stream>>>(hbuf, wqkv, nullptr, nullptr,
                                              qbuf, kbuf, vbuf, 4096, 3072, 1024);

  attn_kernel<<<dim3(32, 16), 256, 0, stream>>>(qbuf, kbuf, vbuf, amask, abuf);

  gemm_k<0><<<dim3(8, 32), 256, 0, stream>>>(abuf, wproj, proj_b, x,
                                             x1, nullptr, nullptr, 4096, 1024, 1024);

  adaln_kernel<<<4096, 256, 0, stream>>>(x1, norm_w, scale_o, shift_o, hbuf);

  gemm_k<2><<<dim3(64, 32), 256, 0, stream>>>(hbuf, wmlp1, mlp_b1, nullptr,
                                              gbuf, nullptr, nullptr, 4096, 8192, 1024);

  gemm_k<0><<<dim3(8, 32), 256, 0, stream>>>(gbuf, wmlp2, mlp_b2, x1,
                                             d_out, nullptr, nullptr, 4096, 1024, 4096);

  (void)in_sizes; (void)n_in; (void)out_size; (void)ws_size;
}

// Round 5
// 506.542 us; speedup vs baseline: 1.3035x; 1.0908x over previous
//
#include <hip/hip_runtime.h>
#include <cstdint>
#include <cstddef>

#define DEVINL __device__ __forceinline__

typedef __bf16 bf16x8 __attribute__((ext_vector_type(8)));
typedef float  f32x4  __attribute__((ext_vector_type(4)));

// ---------------- helpers ----------------

DEVINL unsigned short f2b(float f) {   // f32 -> bf16 bits, round-to-nearest-even
  unsigned u = __builtin_bit_cast(unsigned, f);
  u += 0x7fffu + ((u >> 16) & 1u);
  return (unsigned short)(u >> 16);
}

DEVINL unsigned packtrunc(float a, float b) {  // 2x f32 -> packed bf16 (truncate)
  unsigned ua = __builtin_bit_cast(unsigned, a);
  unsigned ub = __builtin_bit_cast(unsigned, b);
  return (ua >> 16) | (ub & 0xffff0000u);
}

DEVINL void async16(void* lds, const void* g) {
  __builtin_amdgcn_global_load_lds((const __attribute__((address_space(1))) unsigned*)g,
                                   (__attribute__((address_space(3))) unsigned*)lds,
                                   16, 0, 0);
}

// ---------------- fused weight f32 -> bf16 cast (all 4 weights, 1 launch) ----------------
// mlp_w1 rows INTERLEAVED: gate row i -> 2i, up row i -> 2i+1 (GLU via shfl_xor(1)).

__global__ void cvt4_kernel(const float* __restrict__ s0, const float* __restrict__ s1,
                            const float* __restrict__ s2, const float* __restrict__ s3,
                            unsigned short* __restrict__ d0, unsigned short* __restrict__ d1,
                            unsigned short* __restrict__ d2, unsigned short* __restrict__ d3) {
  int i = blockIdx.x * 256 + threadIdx.x;   // float4 index, total 4194304
  if (i < 786432) {
    float4 v = ((const float4*)s0)[i];
    ushort4 o; o.x = f2b(v.x); o.y = f2b(v.y); o.z = f2b(v.z); o.w = f2b(v.w);
    ((ushort4*)d0)[i] = o;
  } else if (i < 1048576) {
    int off = i - 786432;
    float4 v = ((const float4*)s1)[off];
    ushort4 o; o.x = f2b(v.x); o.y = f2b(v.y); o.z = f2b(v.z); o.w = f2b(v.w);
    ((ushort4*)d1)[off] = o;
  } else if (i < 3145728) {
    int off = i - 1048576;                  // mlp_w1: 8192 rows x 256 float4
    int row = off >> 8, col = off & 255;
    int rp = (row < 4096) ? (row << 1) : (((row - 4096) << 1) | 1);
    float4 v = ((const float4*)s2)[off];
    ushort4 o; o.x = f2b(v.x); o.y = f2b(v.y); o.z = f2b(v.z); o.w = f2b(v.w);
    ((ushort4*)d2)[rp * 256 + col] = o;
  } else {
    int off = i - 3145728;
    float4 v = ((const float4*)s3)[off];
    ushort4 o; o.x = f2b(v.x); o.y = f2b(v.y); o.z = f2b(v.z); o.w = f2b(v.w);
    ((ushort4*)d3)[off] = o;
  }
}

// ---------------- conditioning: silu(c) @ {shift,scale}_w^T + b ----------------

__global__ void cond_kernel(const float* __restrict__ c,
                            const float* __restrict__ scale_w, const float* __restrict__ scale_b,
                            const float* __restrict__ shift_w, const float* __restrict__ shift_b,
                            float* __restrict__ scale_o, float* __restrict__ shift_o) {
  __shared__ float sc[1024];
  __shared__ float red[2][4][64];
  int tid = threadIdx.x;
  int b = blockIdx.x >> 4, ch = blockIdx.x & 15;
  for (int i = tid; i < 1024; i += 256) {
    float cv = c[b * 1024 + i];
    sc[i] = cv / (1.f + __expf(-cv));
  }
  __syncthreads();
  int colidx = tid & 63, p = tid >> 6;
  int co = ch * 64 + colidx;
  float dsc = 0.f, dsh = 0.f;
  for (int i = 0; i < 256; ++i) {
    int kk = p * 256 + i;
    float s = sc[kk];
    dsc += s * scale_w[(size_t)co * 1024 + kk];
    dsh += s * shift_w[(size_t)co * 1024 + kk];
  }
  red[0][p][colidx] = dsc;
  red[1][p][colidx] = dsh;
  __syncthreads();
  if (p == 0) {
    float s4  = red[0][0][colidx] + red[0][1][colidx] + red[0][2][colidx] + red[0][3][colidx];
    float sh4 = red[1][0][colidx] + red[1][1][colidx] + red[1][2][colidx] + red[1][3][colidx];
    scale_o[b * 1024 + co] = fminf(fmaxf(s4 + scale_b[co] + 1.f, 0.1f), 10.f);
    shift_o[b * 1024 + co] = sh4 + shift_b[co];
  }
}

// ---------------- adaLN ----------------

__global__ __launch_bounds__(256) void adaln_kernel(const float* __restrict__ x,
                                                    const float* __restrict__ norm_w,
                                                    const float* __restrict__ scale,
                                                    const float* __restrict__ shift,
                                                    unsigned short* __restrict__ h) {
  int row = blockIdx.x;
  int b = row >> 11;
  int tid = threadIdx.x;
  float4 v = ((const float4*)(x + (size_t)row * 1024))[tid];
  float ss = v.x * v.x + v.y * v.y + v.z * v.z + v.w * v.w;
  #pragma unroll
  for (int d = 32; d; d >>= 1) ss += __shfl_xor(ss, d);
  __shared__ float wsum[4];
  if ((tid & 63) == 0) wsum[tid >> 6] = ss;
  __syncthreads();
  float tot = wsum[0] + wsum[1] + wsum[2] + wsum[3];
  float inv = 1.f / fmaxf(sqrtf(tot * (1.f / 1024.f)), 1e-6f);
  float4 nw  = ((const float4*)norm_w)[tid];
  float4 scv = ((const float4*)(scale + b * 1024))[tid];
  float4 shv = ((const float4*)(shift + b * 1024))[tid];
  ushort4 o;
  o.x = f2b(v.x * inv * nw.x * scv.x + shv.x);
  o.y = f2b(v.y * inv * nw.y * scv.y + shv.y);
  o.z = f2b(v.z * inv * nw.z * scv.z + shv.z);
  o.w = f2b(v.w * inv * nw.w * scv.w + shv.w);
  ((ushort4*)(h + (size_t)row * 1024))[tid] = o;
}

// ---------------- MT x 128 bf16 MFMA GEMM:  C = A[M,K] @ B[N,K]^T ----------------
// BK=64 as two independent BK=32 half-buffers (keeps global_load_lds layout
// contiguous = conflict-free). 32 MFMA per barrier-pair. Single accumulator.
// EPI 0: out0(f32) = acc + bias0[col] + resid
// EPI 1: QKV scatter via LDS stage: q(x0.125),k [B,H,N,D]; v [B,H,D,N] (MT=128 only)
// EPI 2: interleaved GLU -> bf16 [M, N/2] (MT=128 only)

template<int EPI, int MT>
__global__ __launch_bounds__(256, 1) void gemm_k(
    const unsigned short* __restrict__ A,
    const unsigned short* __restrict__ B0,
    const float* __restrict__ bias0,
    const float* __restrict__ resid,
    void* __restrict__ out0_, void* __restrict__ out1_, void* __restrict__ out2_,
    int M, int N, int K) {
  constexpr int MI = MT / 32;              // m-frags per wave
  constexpr int A_SH = MT * 32;            // shorts per A half-buffer
  constexpr int COMPUTE_SH = 2 * A_SH + 2 * 4096;
  constexpr int STAGE_SH = (EPI == 1) ? 128 * 136 : (EPI == 2 ? 128 * 72 : 0);
  constexpr int SMEM_SH = (COMPUTE_SH > STAGE_SH) ? COMPUTE_SH : STAGE_SH;
  __shared__ __align__(16) unsigned short smem[SMEM_SH];
  unsigned short* As0 = smem;
  unsigned short* As1 = smem + A_SH;
  unsigned short* Bs0 = smem + 2 * A_SH;
  unsigned short* Bs1 = smem + 2 * A_SH + 4096;

  const int tid = threadIdx.x;
  const int wave = tid >> 6, lane = tid & 63;
  const int quad = lane >> 4, l16 = lane & 15;
  const int wm = (wave >> 1) * (MT / 2), wn = (wave & 1) * 64;
  const int bm = blockIdx.y * MT, bn = blockIdx.x * 128;

  f32x4 acc[MI][4] = {};

  const int steps = K >> 6;
  for (int s = 0; s < steps; ++s) {
    const int k0 = s << 6;
    __syncthreads();
    #pragma unroll
    for (int i = 0; i < MT / 64; ++i) {
      int cc = i * 256 + tid;
      int r = cc >> 2, ko = (cc & 3) << 3;
      size_t ga = (size_t)(bm + r) * K + k0 + ko;
      async16(As0 + (i * 2048 + wave * 512), A + ga);
      async16(As1 + (i * 2048 + wave * 512), A + ga + 32);
    }
    #pragma unroll
    for (int i = 0; i < 2; ++i) {
      int cc = i * 256 + tid;
      int r = cc >> 2, ko = (cc & 3) << 3;
      size_t gb = (size_t)(bn + r) * K + k0 + ko;
      async16(Bs0 + (i * 2048 + wave * 512), B0 + gb);
      async16(Bs1 + (i * 2048 + wave * 512), B0 + gb + 32);
    }
    __syncthreads();
    #pragma unroll
    for (int ks = 0; ks < 2; ++ks) {
      const unsigned short* Ah = ks ? As1 : As0;
      const unsigned short* Bh = ks ? Bs1 : Bs0;
      bf16x8 af[MI], bfr[4];
      #pragma unroll
      for (int mi = 0; mi < MI; ++mi)
        af[mi] = *reinterpret_cast<const bf16x8*>(&Ah[(wm + mi * 16 + l16) * 32 + quad * 8]);
      #pragma unroll
      for (int ni = 0; ni < 4; ++ni)
        bfr[ni] = *reinterpret_cast<const bf16x8*>(&Bh[(wn + ni * 16 + l16) * 32 + quad * 8]);
      #pragma unroll
      for (int mi = 0; mi < MI; ++mi)
        #pragma unroll
        for (int ni = 0; ni < 4; ++ni)
          acc[mi][ni] = __builtin_amdgcn_mfma_f32_16x16x32_bf16(af[mi], bfr[ni], acc[mi][ni], 0, 0, 0);
    }
  }

  // ---------- epilogue: C/D layout col=lane&15, row=quad*4+reg ----------
  if constexpr (EPI == 0) {
    #pragma unroll
    for (int mi = 0; mi < MI; ++mi) {
      #pragma unroll
      for (int ni = 0; ni < 4; ++ni) {
        int gc = bn + wn + ni * 16 + l16;
        #pragma unroll
        for (int r = 0; r < 4; ++r) {
          int gr = bm + wm + mi * 16 + quad * 4 + r;
          ((float*)out0_)[(size_t)gr * N + gc] = acc[mi][ni][r] + bias0[gc] + resid[(size_t)gr * N + gc];
        }
      }
    }
  } else if constexpr (EPI == 1) {
    const int region = bn >> 10;          // 0=q, 1=k, 2=v
    __syncthreads();
    #pragma unroll
    for (int mi = 0; mi < MI; ++mi) {
      #pragma unroll
      for (int ni = 0; ni < 4; ++ni) {
        int lc = wn + ni * 16 + l16;
        #pragma unroll
        for (int r = 0; r < 4; ++r) {
          int lr = wm + mi * 16 + quad * 4 + r;
          float v = acc[mi][ni][r];
          if (region == 0)      smem[lr * 136 + lc] = f2b(v * 0.125f);
          else if (region == 1) smem[lr * 136 + lc] = f2b(v);
          else                  smem[lc * 136 + lr] = f2b(v);   // transpose for v
        }
      }
    }
    __syncthreads();
    const int b = bm >> 11;
    const int bnm = bn & 1023;
    if (region <= 1) {
      int lr = tid >> 1, hl = tid & 1;
      int n = (bm + lr) & 2047;
      int hh = (bnm >> 6) + hl;
      unsigned short* dst = (unsigned short*)(region == 0 ? out0_ : out1_) +
                            (((size_t)(b * 16 + hh)) * 2048 + n) * 64;
      const unsigned short* src = smem + lr * 136 + hl * 64;
      #pragma unroll
      for (int j = 0; j < 8; ++j)
        ((uint4*)dst)[j] = *(const uint4*)(src + j * 8);
    } else {
      int lc = tid >> 1, nh = tid & 1;
      int c2 = bnm + lc;
      int hh = c2 >> 6, d = c2 & 63;
      int nbase = (bm & 2047) + nh * 64;
      unsigned short* dst = (unsigned short*)out2_ +
                            (((size_t)(b * 16 + hh)) * 64 + d) * 2048 + nbase;
      const unsigned short* src = smem + lc * 136 + nh * 64;
      #pragma unroll
      for (int j = 0; j < 8; ++j)
        ((uint4*)dst)[j] = *(const uint4*)(src + j * 8);
    }
  } else {   // EPI 2: interleaved GLU -> bf16 [M, N/2]
    __syncthreads();
    #pragma unroll
    for (int mi = 0; mi < MI; ++mi) {
      #pragma unroll
      for (int ni = 0; ni < 4; ++ni) {
        int lc = wn + ni * 16 + l16;
        int gcp = bn + lc;
        int gi = gcp >> 1;
        float bias = bias0[(gcp & 1) ? 4096 + gi : gi];
        #pragma unroll
        for (int r = 0; r < 4; ++r) {
          int lr = wm + mi * 16 + quad * 4 + r;
          float v = acc[mi][ni][r] + bias;
          float p = __shfl_xor(v, 1);
          if ((l16 & 1) == 0) {
            float g = (v / (1.f + __expf(-v))) * p;
            smem[lr * 72 + (lc >> 1)] = f2b(g);
          }
        }
      }
    }
    __syncthreads();
    int lr = tid >> 1, ch = (tid & 1) * 32;
    unsigned short* dst = (unsigned short*)out0_ + (size_t)(bm + lr) * (N >> 1) + (bn >> 1) + ch;
    const unsigned short* src = smem + lr * 72 + ch;
    #pragma unroll
    for (int j = 0; j < 4; ++j)
      ((uint4*)dst)[j] = *(const uint4*)(src + j * 8);
  }
}

// ---------------- flash attention (S^T formulation, Q-tile 128) ----------------

__global__ __launch_bounds__(256, 1) void attn_kernel(
    const unsigned short* __restrict__ q, const unsigned short* __restrict__ k,
    const unsigned short* __restrict__ vt, const int* __restrict__ amask,
    unsigned short* __restrict__ o) {
  const int bh = blockIdx.x;
  const int b = bh >> 4, h = bh & 15;
  const int qt = blockIdx.y;
  const int tid = threadIdx.x;
  const int wave = tid >> 6, lane = tid & 63;
  const int quad = lane >> 4, l16 = lane & 15;
  const int h7 = l16 & 7;
  const int kc0 = (quad ^ h7) * 8;
  const int kc1 = ((quad + 4) ^ h7) * 8;

  const unsigned short* qb = q  + (size_t)bh * 2048 * 64;
  const unsigned short* kb = k  + (size_t)bh * 2048 * 64;
  const unsigned short* vb = vt + (size_t)bh * 64 * 2048;

  __shared__ __align__(16) unsigned short Ks[64 * 64];
  __shared__ __align__(16) unsigned short Vs[64 * 64];
  __shared__ __align__(16) unsigned short Ps[4 * 2 * 16 * 72];
  __shared__ float biasf[64];

  unsigned short* Psm[2] = { Ps + wave * 2304, Ps + wave * 2304 + 1152 };

  bf16x8 qa[2][2];
  #pragma unroll
  for (int m = 0; m < 2; ++m) {
    int qrow = qt * 128 + wave * 32 + m * 16 + l16;
    qa[m][0] = *reinterpret_cast<const bf16x8*>(&qb[(size_t)qrow * 64 + quad * 8]);
    qa[m][1] = *reinterpret_cast<const bf16x8*>(&qb[(size_t)qrow * 64 + 32 + quad * 8]);
  }

  f32x4 oacc[2][4] = {};
  float mrow[2] = {-30000.f, -30000.f}, lrow[2] = {0.f, 0.f};

  uint4 kpre[2], vpre[2];
  #pragma unroll
  for (int i = 0; i < 2; ++i) {
    int cc = i * 256 + tid;
    int key = cc >> 3, dl = (cc & 7) ^ (key & 7);
    kpre[i] = *(const uint4*)(kb + key * 64 + dl * 8);
    int d = cc >> 3, kl = (cc & 7) ^ (d & 7);
    vpre[i] = *(const uint4*)(vb + (size_t)d * 2048 + kl * 8);
  }
  int mv = (tid < 64) ? amask[b * 2048 + tid] : 0;

  for (int kt = 0; kt < 32; ++kt) {
    __syncthreads();
    ((uint4*)Ks)[tid]       = kpre[0];
    ((uint4*)Ks)[256 + tid] = kpre[1];
    ((uint4*)Vs)[tid]       = vpre[0];
    ((uint4*)Vs)[256 + tid] = vpre[1];
    if (tid < 64) biasf[tid] = mv ? 0.f : -30000.f;
    __syncthreads();

    if (kt + 1 < 32) {
      #pragma unroll
      for (int i = 0; i < 2; ++i) {
        int cc = i * 256 + tid;
        int key = cc >> 3, dl = (cc & 7) ^ (key & 7);
        kpre[i] = *(const uint4*)(kb + (size_t)(kt + 1) * 4096 + key * 64 + dl * 8);
        int d = cc >> 3, kl = (cc & 7) ^ (d & 7);
        vpre[i] = *(const uint4*)(vb + (size_t)d * 2048 + (kt + 1) * 64 + kl * 8);
      }
      mv = (tid < 64) ? amask[b * 2048 + (kt + 1) * 64 + tid] : 0;
    }

    f32x4 st[2][4];
    #pragma unroll
    for (int nt = 0; nt < 4; ++nt) {
      bf16x8 ka0 = *reinterpret_cast<const bf16x8*>(&Ks[(nt * 16 + l16) * 64 + kc0]);
      bf16x8 ka1 = *reinterpret_cast<const bf16x8*>(&Ks[(nt * 16 + l16) * 64 + kc1]);
      f32x4 bv = *reinterpret_cast<const f32x4*>(&biasf[nt * 16 + quad * 4]);
      #pragma unroll
      for (int m = 0; m < 2; ++m) {
        f32x4 z = {};
        z = __builtin_amdgcn_mfma_f32_16x16x32_bf16(ka0, qa[m][0], z, 0, 0, 0);
        z = __builtin_amdgcn_mfma_f32_16x16x32_bf16(ka1, qa[m][1], z, 0, 0, 0);
        st[m][nt] = z + bv;
      }
    }

    #pragma unroll
    for (int m = 0; m < 2; ++m) {
      float tm = -1e30f;
      #pragma unroll
      for (int nt = 0; nt < 4; ++nt)
        #pragma unroll
        for (int r = 0; r < 4; ++r) tm = fmaxf(tm, st[m][nt][r]);
      tm = fmaxf(tm, __shfl_xor(tm, 16));
      tm = fmaxf(tm, __shfl_xor(tm, 32));

      float mnew = fmaxf(mrow[m], tm);
      float alpha = __expf(mrow[m] - mnew);
      mrow[m] = mnew;

      float rs = 0.f;
      #pragma unroll
      for (int nt = 0; nt < 4; ++nt) {
        float p0 = __expf(st[m][nt][0] - mnew);
        float p1 = __expf(st[m][nt][1] - mnew);
        float p2 = __expf(st[m][nt][2] - mnew);
        float p3 = __expf(st[m][nt][3] - mnew);
        rs += (p0 + p1) + (p2 + p3);
        uint2 w;
        w.x = packtrunc(p0, p1);
        w.y = packtrunc(p2, p3);
        *(uint2*)&Psm[m][l16 * 72 + nt * 16 + quad * 4] = w;
      }
      rs += __shfl_xor(rs, 16);
      rs += __shfl_xor(rs, 32);
      lrow[m] = lrow[m] * alpha + rs;

      float a0 = __shfl(alpha, quad * 4 + 0);
      float a1 = __shfl(alpha, quad * 4 + 1);
      float a2 = __shfl(alpha, quad * 4 + 2);
      float a3 = __shfl(alpha, quad * 4 + 3);
      #pragma unroll
      for (int dt = 0; dt < 4; ++dt) {
        oacc[m][dt][0] *= a0; oacc[m][dt][1] *= a1;
        oacc[m][dt][2] *= a2; oacc[m][dt][3] *= a3;
      }
    }

    bf16x8 pa[2][2];
    #pragma unroll
    for (int m = 0; m < 2; ++m) {
      pa[m][0] = *reinterpret_cast<const bf16x8*>(&Psm[m][l16 * 72 + quad * 8]);
      pa[m][1] = *reinterpret_cast<const bf16x8*>(&Psm[m][l16 * 72 + 32 + quad * 8]);
    }
    #pragma unroll
    for (int dt = 0; dt < 4; ++dt) {
      bf16x8 vb0 = *reinterpret_cast<const bf16x8*>(&Vs[(dt * 16 + l16) * 64 + kc0]);
      bf16x8 vb1 = *reinterpret_cast<const bf16x8*>(&Vs[(dt * 16 + l16) * 64 + kc1]);
      #pragma unroll
      for (int m = 0; m < 2; ++m) {
        oacc[m][dt] = __builtin_amdgcn_mfma_f32_16x16x32_bf16(pa[m][0], vb0, oacc[m][dt], 0, 0, 0);
        oacc[m][dt] = __builtin_amdgcn_mfma_f32_16x16x32_bf16(pa[m][1], vb1, oacc[m][dt], 0, 0, 0);
      }
    }
  }

  float iv[2][4];
  #pragma unroll
  for (int m = 0; m < 2; ++m) {
    float invl = lrow[m] > 0.f ? 1.f / lrow[m] : 0.f;
    #pragma unroll
    for (int r = 0; r < 4; ++r) iv[m][r] = __shfl(invl, quad * 4 + r);
  }
  __syncthreads();
  #pragma unroll
  for (int m = 0; m < 2; ++m)
    #pragma unroll
    for (int dt = 0; dt < 4; ++dt)
      #pragma unroll
      for (int r = 0; r < 4; ++r) {
        int lr = wave * 32 + m * 16 + quad * 4 + r;
        Ps[lr * 72 + dt * 16 + l16] = f2b(oacc[m][dt][r] * iv[m][r]);
      }
  __syncthreads();
  {
    int lr = tid >> 1, cb = (tid & 1) * 32;
    int n = qt * 128 + lr;
    unsigned short* dst = o + ((size_t)(b * 2048 + n)) * 1024 + h * 64 + cb;
    const unsigned short* src = Ps + lr * 72 + cb;
    #pragma unroll
    for (int j = 0; j < 4; ++j)
      ((uint4*)dst)[j] = *(const uint4*)(src + j * 8);
  }
}

// ---------------- launch ----------------

extern "C" void kernel_launch(void* const* d_in, const int* in_sizes, int n_in,
                              void* d_out, int out_size, void* d_ws, size_t ws_size,
                              hipStream_t stream) {
  const float* x       = (const float*)d_in[0];
  const float* c       = (const float*)d_in[1];
  const int*   amask   = (const int*)d_in[2];
  const float* norm_w  = (const float*)d_in[3];
  const float* scale_w = (const float*)d_in[4];
  const float* scale_b = (const float*)d_in[5];
  const float* shift_w = (const float*)d_in[6];
  const float* shift_b = (const float*)d_in[7];
  const float* qkv_w   = (const float*)d_in[8];
  const float* proj_w  = (const float*)d_in[9];
  const float* proj_b  = (const float*)d_in[10];
  const float* mlp_w1  = (const float*)d_in[11];
  const float* mlp_b1  = (const float*)d_in[12];
  const float* mlp_w2  = (const float*)d_in[13];
  const float* mlp_b2  = (const float*)d_in[14];

  char* ws = (char*)d_ws;
  unsigned short* wqkv  = (unsigned short*)(ws + 0);
  unsigned short* wproj = (unsigned short*)(ws + 6291456);
  unsigned short* wmlp1 = (unsigned short*)(ws + 8388608);   // interleaved gate/up rows
  unsigned short* wmlp2 = (unsigned short*)(ws + 25165824);
  float* scale_o        = (float*)(ws + 33554432);
  float* shift_o        = (float*)(ws + 33562624);
  unsigned short* hbuf  = (unsigned short*)(ws + 33570816);
  unsigned short* qbuf  = (unsigned short*)(ws + 41959424);
  unsigned short* kbuf  = (unsigned short*)(ws + 50348032);
  unsigned short* vbuf  = (unsigned short*)(ws + 58736640);
  unsigned short* abuf  = (unsigned short*)(ws + 67125248);
  unsigned short* gbuf  = qbuf;
  float* x1             = (float*)(ws + 75513856);

  cvt4_kernel<<<16384, 256, 0, stream>>>(qkv_w, proj_w, mlp_w1, mlp_w2,
                                         wqkv, wproj, wmlp1, wmlp2);

  cond_kernel<<<32, 256, 0, stream>>>(c, scale_w, scale_b, shift_w, shift_b, scale_o, shift_o);

  adaln_kernel<<<4096, 256, 0, stream>>>(x, norm_w, scale_o, shift_o, hbuf);

  gemm_k<1, 128><<<dim3(24, 32), 256, 0, stream>>>(hbuf, wqkv, nullptr, nullptr,
                                                   qbuf, kbuf, vbuf, 4096, 3072, 1024);

  attn_kernel<<<dim3(32, 16), 256, 0, stream>>>(qbuf, kbuf, vbuf, amask, abuf);

  gemm_k<0, 64><<<dim3(8, 64), 256, 0, stream>>>(abuf, wproj, proj_b, x,
                                                 x1, nullptr, nullptr, 4096, 1024, 1024);

  adaln_kernel<<<4096, 256, 0, stream>>>(x1, norm_w, scale_o, shift_o, hbuf);

  gemm_k<2, 128><<<dim3(64, 32), 256, 0, stream>>>(hbuf, wmlp1, mlp_b1, nullptr,
                                                   gbuf, nullptr, nullptr, 4096, 8192, 1024);

  gemm_k<0, 64><<<dim3(8, 64), 256, 0, stream>>>(gbuf, wmlp2, mlp_b2, x1,
                                                 d_out, nullptr, nullptr, 4096, 1024, 4096);

  (void)in_sizes; (void)n_in; (void)out_size; (void)ws_size;
}